// Round 1
// baseline (1027.656 us; speedup 1.0000x reference)
//
#include <hip/hip_runtime.h>

// ---------------------------------------------------------------------------
// Sudoku GCN, fully fused. 2 batch items per block, h resident in LDS.
// h_{l+1} = relu( (A_norm h_l) W_l + b_l );  A_norm = (A+I)/21 (deg uniform 21)
// Aggregation done BEFORE GEMM (associativity), in f32, exact decomposition:
//   (A h)[i,j] = R[i] + C[j] + Box[bi,bj] - rowbox[i,bj] - colbox[bi,j]
// GEMM in bf16 MFMA with hi/lo split (3 products) -> ~17-bit mantissa.
// Layer 1 collapsed: (A h0) W1 = Cnt[81x10] @ U,  U = relu(W_in+b_in)@W1/21.
// ---------------------------------------------------------------------------

typedef short  s16x8 __attribute__((ext_vector_type(8)));
typedef unsigned short u16x8 __attribute__((ext_vector_type(8)));
typedef float  f32x4 __attribute__((ext_vector_type(4)));

#define G_LO     49152      // lo plane of h/g buffer (192 rows * 256B per plane)
#define W_OFF    98304      // W buffer start
#define W_PLANE  32768      // 128 cols * 256B per plane
#define XS_OFF   48128      // x cache inside garbage rows (188..191) of hi plane
#define V_OFF    41472      // fallback V = relu(Win+bin), rows 162..181 of hi plane
#define LDS_TOTAL 163840    // 160 KiB exactly

__device__ __forceinline__ unsigned short f2bf(float f) {      // RTNE f32->bf16
  unsigned u = __builtin_bit_cast(unsigned, f);
  u += 0x7FFFu + ((u >> 16) & 1u);
  return (unsigned short)(u >> 16);
}
__device__ __forceinline__ float bf2f(unsigned short h) {
  unsigned u = ((unsigned)h) << 16;
  return __builtin_bit_cast(float, u);
}
__device__ __forceinline__ f32x4 mfma16(u16x8 a, u16x8 b, f32x4 c) {
  return __builtin_amdgcn_mfma_f32_16x16x32_bf16(
      __builtin_bit_cast(s16x8, a), __builtin_bit_cast(s16x8, b), c, 0, 0, 0);
}
// element (row,col) byte offset in h/g buffer (per plane), 16B-slot XOR swizzle
__device__ __forceinline__ int g_off(int row, int col) {
  return row * 256 + ((((col >> 3) ^ row) & 15) << 4) + ((col & 7) << 1);
}
// element (col,k) byte offset in W buffer hi plane (Wt stored col-major over k)
__device__ __forceinline__ int w_off(int col, int k) {
  return W_OFF + col * 256 + ((((k >> 3) ^ col) & 15) << 4) + ((k & 7) << 1);
}

// ---------------- setup: U[10][128] = relu(Win+bin) @ W1 / 21 ----------------
extern "C" __global__ void gnn_setup(const float* __restrict__ Win,
                                     const float* __restrict__ bin,
                                     const float* __restrict__ W1,
                                     float* __restrict__ U) {
  __shared__ float V[1280];
  int t = threadIdx.x;
#pragma unroll
  for (int q = 0; q < 5; ++q) {
    int idx = t + 256 * q;
    V[idx] = fmaxf(Win[idx] + bin[idx & 127], 0.f);
  }
  __syncthreads();
#pragma unroll
  for (int p = 0; p < 5; ++p) {
    int o = t + 256 * p;
    int d = o >> 7, c = o & 127;
    float s = 0.f;
    for (int f = 0; f < 128; ++f) s += V[d * 128 + f] * W1[f * 128 + c];
    U[o] = s * (1.f / 21.f);
  }
}

// --------------------------------- main -------------------------------------
extern "C" __global__ void __launch_bounds__(512, 1)
gnn_fused(const int* __restrict__ x, const float* __restrict__ Wl,
          const float* __restrict__ bl, const float* __restrict__ Wout,
          const float* __restrict__ bout, const float* __restrict__ U,
          const float* __restrict__ Win, const float* __restrict__ bin,
          float* __restrict__ out, int nB) {
  extern __shared__ char lds[];
  const int t = threadIdx.x;
  const int lane = t & 63;
  const int w = t >> 6;            // wave 0..7
  const int b0 = blockIdx.x * 2;   // two batch items per block
  const int mh = w >> 1;           // m quarter: 3 of 12 m-tiles
  const int nh = w & 1;            // n half: 64 cols

  // ---- phase 0: cache x (and fallback V) ----
  if (t < 162) {
    int idx = b0 * 81 + t;
    ((int*)(lds + XS_OFF))[t] = (idx < nB * 81) ? x[idx] : 0;
  }
  if (!U) {
    for (int q = 0; q < 3; ++q) {
      int idx = t + 512 * q;
      if (idx < 1280)
        ((float*)(lds + V_OFF))[idx] = fmaxf(Win[idx] + bin[idx & 127], 0.f);
    }
  }
  __syncthreads();

  // ---- phase 1: digit counts -> g rows (hi plane, lo never read in L1);
  //               stage U (K=32, zero-padded) into W buffer ----
  if (t < 162) {
    const int* xs = (const int*)(lds + XS_OFF);
    int item = (t >= 81);
    int n = t - 81 * item;
    int i = n / 9, j = n - 9 * i;
    int bi = (i / 3) * 3, bj = (j / 3) * 3;
    int base = 81 * item;
    int rv[9], cv[9], bv[9], rb3[3], cb3[3];
#pragma unroll
    for (int k = 0; k < 9; ++k) rv[k] = xs[base + i * 9 + k];
#pragma unroll
    for (int k = 0; k < 9; ++k) cv[k] = xs[base + k * 9 + j];
#pragma unroll
    for (int r2 = 0; r2 < 3; ++r2)
#pragma unroll
      for (int c2 = 0; c2 < 3; ++c2)
        bv[r2 * 3 + c2] = xs[base + (bi + r2) * 9 + (bj + c2)];
#pragma unroll
    for (int k = 0; k < 3; ++k) rb3[k] = xs[base + i * 9 + bj + k];
#pragma unroll
    for (int k = 0; k < 3; ++k) cb3[k] = xs[base + (bi + k) * 9 + j];
    unsigned short cnt[16];
#pragma unroll
    for (int d = 0; d < 10; ++d) {
      int c = 0;
#pragma unroll
      for (int k = 0; k < 9; ++k) c += (rv[k] == d) + (cv[k] == d) + (bv[k] == d);
#pragma unroll
      for (int k = 0; k < 3; ++k) c -= (rb3[k] == d) + (cb3[k] == d);
      cnt[d] = f2bf((float)c);   // integers <=21: exact in bf16
    }
#pragma unroll
    for (int d = 10; d < 16; ++d) cnt[d] = 0;
    int row = t;
    u16x8 c0, c1, z;
#pragma unroll
    for (int e = 0; e < 8; ++e) { c0[e] = cnt[e]; c1[e] = cnt[8 + e]; z[e] = 0; }
    *(u16x8*)(lds + row * 256 + (((0 ^ row) & 15) << 4)) = c0;
    *(u16x8*)(lds + row * 256 + (((1 ^ row) & 15) << 4)) = c1;
    *(u16x8*)(lds + row * 256 + (((2 ^ row) & 15) << 4)) = z;
    *(u16x8*)(lds + row * 256 + (((3 ^ row) & 15) << 4)) = z;
  }
  {
    int c = t & 127, kh = t >> 7;  // kh 0..3
    if (U) {
#pragma unroll
      for (int q = 0; q < 8; ++q) {
        int k = kh * 8 + q;
        float v = (k < 10) ? U[k * 128 + c] : 0.f;
        unsigned short hi = f2bf(v);
        unsigned short lo = f2bf(v - bf2f(hi));
        *(unsigned short*)(lds + w_off(c, k)) = hi;
        *(unsigned short*)(lds + W_PLANE + w_off(c, k)) = lo;
      }
    } else {
      const float* V = (const float*)(lds + V_OFF);
      for (int k = kh; k < 10; k += 4) {
        float s = 0.f;
        for (int f = 0; f < 128; ++f) s += V[k * 128 + f] * Wl[f * 128 + c];
        s *= (1.f / 21.f);
        unsigned short hi = f2bf(s);
        unsigned short lo = f2bf(s - bf2f(hi));
        *(unsigned short*)(lds + w_off(c, k)) = hi;
        *(unsigned short*)(lds + W_PLANE + w_off(c, k)) = lo;
      }
      for (int k = 10 + kh; k < 32; k += 4) {
        *(unsigned short*)(lds + w_off(c, k)) = 0;
        *(unsigned short*)(lds + W_PLANE + w_off(c, k)) = 0;
      }
    }
  }
  __syncthreads();

  f32x4 acc[3][4];
  const int rsel = lane & 15;

  auto epilogue = [&](const float* bvec) {
    float bias[4];
#pragma unroll
    for (int nt = 0; nt < 4; ++nt) bias[nt] = bvec[nh * 64 + nt * 16 + rsel];
    __syncthreads();   // all frag reads done before overwriting buffer
#pragma unroll
    for (int mt = 0; mt < 3; ++mt) {
#pragma unroll
      for (int nt = 0; nt < 4; ++nt) {
        int col = nh * 64 + nt * 16 + rsel;
#pragma unroll
        for (int r = 0; r < 4; ++r) {
          int row = (mh * 3 + mt) * 16 + (lane >> 4) * 4 + r;
          if (row < 162) {
            float v = fmaxf(acc[mt][nt][r] + bias[nt], 0.f);
            unsigned short hi = f2bf(v);
            unsigned short lo = f2bf(v - bf2f(hi));
            int off = g_off(row, col);
            *(unsigned short*)(lds + off) = hi;
            *(unsigned short*)(lds + G_LO + off) = lo;
          }
        }
      }
    }
  };

  // ---- layer 1 GEMM: K=32, A=Cnt exact (hi only) => 2 products ----
#pragma unroll
  for (int a = 0; a < 3; ++a)
#pragma unroll
    for (int b = 0; b < 4; ++b) acc[a][b] = f32x4{0.f, 0.f, 0.f, 0.f};
  {
    int khalf = lane >> 4;
    u16x8 ah[3], bh[4], blo[4];
#pragma unroll
    for (int mt = 0; mt < 3; ++mt) {
      int row = (mh * 3 + mt) * 16 + rsel;
      ah[mt] = *(const u16x8*)(lds + row * 256 + (((khalf ^ rsel) & 15) << 4));
    }
#pragma unroll
    for (int nt = 0; nt < 4; ++nt) {
      int col = nh * 64 + nt * 16 + rsel;
      int off = W_OFF + col * 256 + (((khalf ^ rsel) & 15) << 4);
      bh[nt]  = *(const u16x8*)(lds + off);
      blo[nt] = *(const u16x8*)(lds + W_PLANE + off);
    }
#pragma unroll
    for (int mt = 0; mt < 3; ++mt)
#pragma unroll
      for (int nt = 0; nt < 4; ++nt) acc[mt][nt] = mfma16(ah[mt], bh[nt], acc[mt][nt]);
#pragma unroll
    for (int mt = 0; mt < 3; ++mt)
#pragma unroll
      for (int nt = 0; nt < 4; ++nt) acc[mt][nt] = mfma16(ah[mt], blo[nt], acc[mt][nt]);
  }
  epilogue(bl);

  // ---- layers 2..6 ----
#pragma unroll 1
  for (int l = 1; l < 6; ++l) {
    __syncthreads();   // epilogue writes visible
    {  // stage W_l (transpose + hi/lo split), disjoint from agg's buffer
      int c = t & 127, kh = t >> 7;
      const float* Ws = Wl + l * 16384;
#pragma unroll 4
      for (int kk = 0; kk < 32; ++kk) {
        int k = kh * 32 + kk;
        float v = Ws[k * 128 + c];
        unsigned short hi = f2bf(v);
        unsigned short lo = f2bf(v - bf2f(hi));
        *(unsigned short*)(lds + w_off(c, k)) = hi;
        *(unsigned short*)(lds + W_PLANE + w_off(c, k)) = lo;
      }
    }
    if (t < 256) {  // in-place per-column aggregation: g = (A h) (and *1/21)
      int item = t >> 7, c = t & 127;
      int rbase = item * 81;
      float R[9] = {}, C[9] = {}, BX[9] = {}, RB[27] = {}, CB[27] = {};
#pragma unroll
      for (int n = 0; n < 81; ++n) {
        const int i = n / 9, j = n % 9, bi = i / 3, bj = j / 3;
        int off = g_off(rbase + n, c);
        float v = bf2f(*(const unsigned short*)(lds + off)) +
                  bf2f(*(const unsigned short*)(lds + G_LO + off));
        R[i] += v; C[j] += v; BX[bi * 3 + bj] += v;
        RB[i * 3 + bj] += v; CB[bi * 9 + j] += v;
      }
#pragma unroll
      for (int n = 0; n < 81; ++n) {
        const int i = n / 9, j = n % 9, bi = i / 3, bj = j / 3;
        float g = (R[i] + C[j] + BX[bi * 3 + bj] - RB[i * 3 + bj] - CB[bi * 9 + j]) *
                  (1.f / 21.f);
        unsigned short hi = f2bf(g);
        unsigned short lo = f2bf(g - bf2f(hi));
        int off = g_off(rbase + n, c);
        *(unsigned short*)(lds + off) = hi;
        *(unsigned short*)(lds + G_LO + off) = lo;
      }
    }
    __syncthreads();
    // GEMM K=128, hi/lo split (3 products)
#pragma unroll
    for (int a = 0; a < 3; ++a)
#pragma unroll
      for (int b = 0; b < 4; ++b) acc[a][b] = f32x4{0.f, 0.f, 0.f, 0.f};
#pragma unroll
    for (int ks = 0; ks < 4; ++ks) {
      int slotb = ks * 4 + (lane >> 4);
      int soff = ((slotb ^ rsel) & 15) << 4;
      u16x8 ah[3], al[3], bh[4], blo[4];
#pragma unroll
      for (int mt = 0; mt < 3; ++mt) {
        int row = (mh * 3 + mt) * 16 + rsel;
        ah[mt] = *(const u16x8*)(lds + row * 256 + soff);
        al[mt] = *(const u16x8*)(lds + G_LO + row * 256 + soff);
      }
#pragma unroll
      for (int nt = 0; nt < 4; ++nt) {
        int col = nh * 64 + nt * 16 + rsel;
        bh[nt]  = *(const u16x8*)(lds + W_OFF + col * 256 + soff);
        blo[nt] = *(const u16x8*)(lds + W_OFF + W_PLANE + col * 256 + soff);
      }
#pragma unroll
      for (int mt = 0; mt < 3; ++mt)
#pragma unroll
        for (int nt = 0; nt < 4; ++nt) acc[mt][nt] = mfma16(ah[mt], bh[nt], acc[mt][nt]);
#pragma unroll
      for (int mt = 0; mt < 3; ++mt)
#pragma unroll
        for (int nt = 0; nt < 4; ++nt) acc[mt][nt] = mfma16(ah[mt], blo[nt], acc[mt][nt]);
#pragma unroll
      for (int mt = 0; mt < 3; ++mt)
#pragma unroll
        for (int nt = 0; nt < 4; ++nt) acc[mt][nt] = mfma16(al[mt], bh[nt], acc[mt][nt]);
    }
    epilogue(bl + l * 128);
  }

  // ---- output: logits = h6 @ Wout + bout (N=16 padded from 9) ----
  __syncthreads();
  {
    int col = t & 15, kh = t >> 4;  // stage Wout cols 0..15 (>=9 zero)
#pragma unroll
    for (int q = 0; q < 4; ++q) {
      int k = kh * 4 + q;
      float v = (col < 9) ? Wout[k * 9 + col] : 0.f;
      unsigned short hi = f2bf(v);
      unsigned short lo = f2bf(v - bf2f(hi));
      *(unsigned short*)(lds + w_off(col, k)) = hi;
      *(unsigned short*)(lds + W_PLANE + w_off(col, k)) = lo;
    }
  }
  __syncthreads();
  {
    f32x4 oacc[2];
    oacc[0] = f32x4{0.f, 0.f, 0.f, 0.f};
    oacc[1] = f32x4{0.f, 0.f, 0.f, 0.f};
#pragma unroll
    for (int ks = 0; ks < 4; ++ks) {
      int slotb = ks * 4 + (lane >> 4);
      int soff = ((slotb ^ rsel) & 15) << 4;
      u16x8 bh  = *(const u16x8*)(lds + W_OFF + rsel * 256 + soff);
      u16x8 blo = *(const u16x8*)(lds + W_OFF + W_PLANE + rsel * 256 + soff);
#pragma unroll
      for (int p = 0; p < 2; ++p) {
        int mt = w + 8 * p;       // 12 m-tiles over 8 waves
        if (mt < 12) {
          int aoff = (mt * 16 + rsel) * 256 + soff;
          u16x8 ah = *(const u16x8*)(lds + aoff);
          u16x8 al = *(const u16x8*)(lds + G_LO + aoff);
          oacc[p] = mfma16(ah, bh, oacc[p]);
          oacc[p] = mfma16(ah, blo, oacc[p]);
          oacc[p] = mfma16(al, bh, oacc[p]);
        }
      }
    }
    int o = rsel;
    float bo = (o < 9) ? bout[o] : 0.f;
#pragma unroll
    for (int p = 0; p < 2; ++p) {
      int mt = w + 8 * p;
      if (mt < 12 && o < 9) {
#pragma unroll
        for (int r = 0; r < 4; ++r) {
          int row = mt * 16 + (lane >> 4) * 4 + r;
          if (row < 162) {
            int item = (row >= 81);
            int lr = row - 81 * item;
            int bidx = b0 + item;
            if (bidx < nB) out[bidx * 729 + lr * 9 + o] = oacc[p][r] + bo;
          }
        }
      }
    }
  }
}

// ------------------------------- launcher ------------------------------------
extern "C" void kernel_launch(void* const* d_in, const int* in_sizes, int n_in,
                              void* d_out, int out_size, void* d_ws, size_t ws_size,
                              hipStream_t stream) {
  const int*   x    = (const int*)d_in[0];
  const float* Win  = (const float*)d_in[1];
  const float* bin  = (const float*)d_in[2];
  const float* Wl   = (const float*)d_in[3];
  const float* blay = (const float*)d_in[4];
  const float* Wout = (const float*)d_in[5];
  const float* bout = (const float*)d_in[6];
  float* out = (float*)d_out;
  int nB = in_sizes[0] / 81;

  const float* U = nullptr;
  if (ws_size >= 1280 * sizeof(float)) {
    U = (const float*)d_ws;
    gnn_setup<<<1, 256, 0, stream>>>(Win, bin, Wl, (float*)d_ws);
  }
  hipFuncSetAttribute((const void*)gnn_fused,
                      hipFuncAttributeMaxDynamicSharedMemorySize, LDS_TOTAL);
  int grid = (nB + 1) / 2;
  gnn_fused<<<grid, 512, LDS_TOTAL, stream>>>(x, Wl, blay, Wout, bout, U, Win, bin,
                                              out, nB);
}

// Round 2
// 933.691 us; speedup vs baseline: 1.1006x; 1.1006x over previous
//
#include <hip/hip_runtime.h>

// ---------------------------------------------------------------------------
// Sudoku GCN, fully fused, MFMA-everything.
//   h_{l+1} = relu( (A+I) h_l * (W_l/21) + b_l ),  A+I exact 0/1 in bf16.
// Orientation ping-pong (no transposed reads, all epi writes b64-packed):
//   hbuf = h^T [feat][node] (chunk-major), gbuf = g [node][feat] (chunk-major)
//   agg : g^T = h^T (A+I)     reads hbuf rows, writes gbuf packed
//   gemm: h'  = g (W/21)      reads gbuf rows, writes hbuf packed
//   l=6 : h6^T = W^T g^T      writes h6 as [node][feat] for the output GEMM
// Layer 1 collapsed: h1 = relu(Cnt @ U + b1), U = relu(Win+bin)@W1/21.
// Weights: setup kernels pre-split (bf16 hi/lo, 3-product GEMM) into
// per-wave-coalesced 1KB fragment blobs in d_ws; loaded global->VGPR.
// ---------------------------------------------------------------------------

typedef short          s16x8 __attribute__((ext_vector_type(8)));
typedef unsigned short u16x8 __attribute__((ext_vector_type(8)));
typedef unsigned short u16x4 __attribute__((ext_vector_type(4)));
typedef float          f32x4 __attribute__((ext_vector_type(4)));

#define HB   0        // hbuf: [2 pl][12 chunk][128 feat][16B]  plane stride 24576
#define GB   49152    // gbuf: [2 pl][16 chunk][96 node][16B]   plane stride 24576
#define CNT  98304    // cnt : [4 chunk][96 node][16B] = 6144
#define XC   104448   // x cache: 81 ints
#define LDS_SZ 104832

#define OFF_WB   5120     // [l 0..4][nt 0..7][ks 0..3][pl 0..1] x 1024B
#define OFF_AB   332800   // [nt 0..5][ks 0..2] x 1024B  (A+I, hi only, exact)
#define OFF_UB   351232   // [nt 0..7][pl] x 1024B
#define OFF_WOUT 367616   // [ks 0..3][pl] x 1024B
#define WS_NEED  375808

__device__ __forceinline__ unsigned short f2bf(float f) {   // RTNE f32->bf16
  unsigned u = __builtin_bit_cast(unsigned, f);
  u += 0x7FFFu + ((u >> 16) & 1u);
  return (unsigned short)(u >> 16);
}
__device__ __forceinline__ float bf2f(unsigned short h) {
  unsigned u = ((unsigned)h) << 16;
  return __builtin_bit_cast(float, u);
}
__device__ __forceinline__ f32x4 mfma16(u16x8 a, u16x8 b, f32x4 c) {
  return __builtin_amdgcn_mfma_f32_16x16x32_bf16(
      __builtin_bit_cast(s16x8, a), __builtin_bit_cast(s16x8, b), c, 0, 0, 0);
}
__device__ __forceinline__ void split4(f32x4 v, u16x4& hi, u16x4& lo) {
#pragma unroll
  for (int r = 0; r < 4; ++r) {
    unsigned short h = f2bf(v[r]);
    hi[r] = h;
    lo[r] = f2bf(v[r] - bf2f(h));
  }
}
__device__ __forceinline__ bool adjf(int r, int c) {
  if (r >= 81 || c >= 81) return false;
  int ri = r / 9, rj = r % 9, ci = c / 9, cj = c % 9;
  return ri == ci || rj == cj || (ri / 3 == ci / 3 && rj / 3 == cj / 3);
}
__device__ __forceinline__ u16x8 makeAB(int nt, int ks, int lane) {
  int col = nt * 16 + (lane & 15), k0 = ks * 32 + (lane >> 4) * 8;
  u16x8 r;
#pragma unroll
  for (int i = 0; i < 8; ++i) r[i] = adjf(k0 + i, col) ? 0x3F80 : 0;
  return r;
}

// ---------------- setup1: U[10][128] = relu(Win+bin) @ W1 / 21 (f32, ws+0) ---
extern "C" __global__ void gnn_setup(const float* __restrict__ Win,
                                     const float* __restrict__ bin,
                                     const float* __restrict__ W1,
                                     float* __restrict__ U) {
  __shared__ float V[1280];
  int t = threadIdx.x;
#pragma unroll
  for (int q = 0; q < 5; ++q) {
    int idx = t + 256 * q;
    V[idx] = fmaxf(Win[idx] + bin[idx & 127], 0.f);
  }
  __syncthreads();
#pragma unroll
  for (int p = 0; p < 5; ++p) {
    int o = t + 256 * p;
    int d = o >> 7, c = o & 127;
    float s = 0.f;
    for (int f = 0; f < 128; ++f) s += V[d * 128 + f] * W1[f * 128 + c];
    U[o] = s * (1.f / 21.f);
  }
}

// ---------------- setup2: pack all B/A fragment blobs into ws ----------------
extern "C" __global__ void gnn_pack(const float* __restrict__ Wl,
                                    const float* __restrict__ Wout,
                                    const float* __restrict__ Uscr,
                                    char* __restrict__ G) {
  int unit = blockIdx.x, lane = threadIdx.x;
  int rsel = lane & 15, kh = lane >> 4;
  u16x8 r;
  char* dst;
  if (unit < 320) {                       // WB: ((l*8+nt)*4+ks)*2+pl
    int pl = unit & 1, ks = (unit >> 1) & 3, nt = (unit >> 3) & 7, l = unit >> 6;
    int col = nt * 16 + rsel, k0 = ks * 32 + kh * 8;
    const float* src = Wl + (l + 1) * 16384 + k0 * 128 + col;
#pragma unroll
    for (int i = 0; i < 8; ++i) {
      float v = src[i * 128] * (1.f / 21.f);
      unsigned short h = f2bf(v);
      r[i] = pl ? f2bf(v - bf2f(h)) : h;
    }
    dst = G + OFF_WB + unit * 1024 + lane * 16;
  } else if (unit < 338) {                // AB: nt*3+ks
    int u2 = unit - 320, nt = u2 / 3, ks = u2 % 3;
    r = makeAB(nt, ks, lane);
    dst = G + OFF_AB + u2 * 1024 + lane * 16;
  } else if (unit < 354) {                // UB: nt*2+pl
    int u2 = unit - 338, nt = u2 >> 1, pl = u2 & 1;
    int col = nt * 16 + rsel;
#pragma unroll
    for (int i = 0; i < 8; ++i) {
      int k = kh * 8 + i;
      float v = (k < 10) ? Uscr[k * 128 + col] : 0.f;
      unsigned short h = f2bf(v);
      r[i] = pl ? f2bf(v - bf2f(h)) : h;
    }
    dst = G + OFF_UB + u2 * 1024 + lane * 16;
  } else {                                // WOUT: ks*2+pl
    int u2 = unit - 354, ks = u2 >> 1, pl = u2 & 1;
    int col = rsel, k0 = ks * 32 + kh * 8;
#pragma unroll
    for (int i = 0; i < 8; ++i) {
      float v = (col < 9) ? Wout[(k0 + i) * 9 + col] : 0.f;
      unsigned short h = f2bf(v);
      r[i] = pl ? f2bf(v - bf2f(h)) : h;
    }
    dst = G + OFF_WOUT + u2 * 1024 + lane * 16;
  }
  *(u16x8*)dst = r;
}

// --------------------------------- main -------------------------------------
template <bool PRE>
__global__ void __launch_bounds__(512, 1)
gnn_main(const int* __restrict__ x, const float* __restrict__ Wl,
         const float* __restrict__ bl, const float* __restrict__ Wout,
         const float* __restrict__ bout, const float* __restrict__ ws,
         float* __restrict__ out, int nB) {
  extern __shared__ char lds[];
  const int t = threadIdx.x, lane = t & 63, w = t >> 6;
  const int rsel = lane & 15, kh = lane >> 4;
  const char* G = (const char*)ws;
  const int b = blockIdx.x;

  // wave->tile mappings
  const int mgL = w & 1, ngL = w >> 1;   // L1 : m(node) 3 tiles, n(feat) 2
  const int mg2 = w >> 1, ng2 = w & 1;   // agg + flipped: m 2 tiles, n 3
  const int mgW = w & 1, ngW = w >> 1;   // W   : m(node) 3 tiles, n(feat) 2

  // ---- persistent operand fragments (global -> VGPR) ----
  u16x8 abf[3][3];                       // A+I B-frags (exact, hi only)
#pragma unroll
  for (int j = 0; j < 3; ++j)
#pragma unroll
    for (int ks = 0; ks < 3; ++ks) {
      if constexpr (PRE)
        abf[j][ks] = *(const u16x8*)(G + OFF_AB + ((ng2 * 3 + j) * 3 + ks) * 1024 + lane * 16);
      else
        abf[j][ks] = makeAB(ng2 * 3 + j, ks, lane);
    }
  u16x8 ubf[2][2];                       // U B-frags [j][pl]
#pragma unroll
  for (int j = 0; j < 2; ++j)
#pragma unroll
    for (int pl = 0; pl < 2; ++pl) {
      if constexpr (PRE)
        ubf[j][pl] = *(const u16x8*)(G + OFF_UB + (((ngL * 2 + j) * 2) + pl) * 1024 + lane * 16);
      else {
        int col = (ngL * 2 + j) * 16 + rsel;
        u16x8 r;
#pragma unroll
        for (int i = 0; i < 8; ++i) {
          int k = kh * 8 + i;
          float v = (k < 10) ? ws[k * 128 + col] : 0.f;
          unsigned short h = f2bf(v);
          r[i] = pl ? f2bf(v - bf2f(h)) : h;
        }
        ubf[j][pl] = r;
      }
    }
  u16x8 wbf[2][4][2];                    // W frags [j][ks][pl]
  auto loadWBall = [&](int blob, int ntbase) {
#pragma unroll
    for (int j = 0; j < 2; ++j)
#pragma unroll
      for (int ks = 0; ks < 4; ++ks)
#pragma unroll
        for (int pl = 0; pl < 2; ++pl) {
          if constexpr (PRE) {
            wbf[j][ks][pl] = *(const u16x8*)(
                G + OFF_WB + ((((blob * 8 + (ntbase + j)) * 4 + ks) * 2 + pl) << 10) + lane * 16);
          } else {
            int colw = (ntbase + j) * 16 + rsel, k0 = ks * 32 + kh * 8;
            const float* src = Wl + (blob + 1) * 16384 + k0 * 128 + colw;
            u16x8 r;
#pragma unroll
            for (int i = 0; i < 8; ++i) {
              float v = src[i * 128] * (1.f / 21.f);
              unsigned short h = f2bf(v);
              r[i] = pl ? f2bf(v - bf2f(h)) : h;
            }
            wbf[j][ks][pl] = r;
          }
        }
  };
  loadWBall(0, ngW * 2);                 // layer-1 GCN weights (blob 0)

  float bL1[2];
#pragma unroll
  for (int j = 0; j < 2; ++j) bL1[j] = bl[(ngL * 2 + j) * 16 + rsel];

  // ---- x cache + digit counts -> cntbuf ----
  if (t < 81) ((int*)(lds + XC))[t] = x[b * 81 + t];
  __syncthreads();
  if (t < 96) {
    unsigned short cnt[16];
#pragma unroll
    for (int d = 0; d < 16; ++d) cnt[d] = 0;
    if (t < 81) {
      const int* xs = (const int*)(lds + XC);
      int n = t, i = n / 9, j = n - 9 * i;
      int bi = (i / 3) * 3, bj = (j / 3) * 3;
      int rv[9], cv[9], bv[9], rb3[3], cb3[3];
#pragma unroll
      for (int k = 0; k < 9; ++k) rv[k] = xs[i * 9 + k];
#pragma unroll
      for (int k = 0; k < 9; ++k) cv[k] = xs[k * 9 + j];
#pragma unroll
      for (int r2 = 0; r2 < 3; ++r2)
#pragma unroll
        for (int c2 = 0; c2 < 3; ++c2) bv[r2 * 3 + c2] = xs[(bi + r2) * 9 + (bj + c2)];
#pragma unroll
      for (int k = 0; k < 3; ++k) rb3[k] = xs[i * 9 + bj + k];
#pragma unroll
      for (int k = 0; k < 3; ++k) cb3[k] = xs[(bi + k) * 9 + j];
#pragma unroll
      for (int d = 0; d < 10; ++d) {
        int c = 0;
#pragma unroll
        for (int k = 0; k < 9; ++k) c += (rv[k] == d) + (cv[k] == d) + (bv[k] == d);
#pragma unroll
        for (int k = 0; k < 3; ++k) c -= (rb3[k] == d) + (cb3[k] == d);
        cnt[d] = f2bf((float)c);         // integers <=21: exact in bf16
      }
    }
    u16x8 c0, c1, z;
#pragma unroll
    for (int e = 0; e < 8; ++e) { c0[e] = cnt[e]; c1[e] = cnt[8 + e]; z[e] = 0; }
    *(u16x8*)(lds + CNT + 0 * 1536 + t * 16) = c0;
    *(u16x8*)(lds + CNT + 1 * 1536 + t * 16) = c1;
    *(u16x8*)(lds + CNT + 2 * 1536 + t * 16) = z;
    *(u16x8*)(lds + CNT + 3 * 1536 + t * 16) = z;
  }
  __syncthreads();

  // ---- L1 GEMM: h1 = relu(Cnt @ U + b1) -> hbuf [feat][node] -----
  {
    f32x4 a1[3][2];
#pragma unroll
    for (int mt = 0; mt < 3; ++mt)
#pragma unroll
      for (int j = 0; j < 2; ++j) a1[mt][j] = f32x4{0.f, 0.f, 0.f, 0.f};
#pragma unroll
    for (int mt = 0; mt < 3; ++mt) {
      int node = (mgL * 3 + mt) * 16 + rsel;
      u16x8 af = *(const u16x8*)(lds + CNT + kh * 1536 + node * 16);
#pragma unroll
      for (int j = 0; j < 2; ++j) {
        a1[mt][j] = mfma16(af, ubf[j][0], a1[mt][j]);
        a1[mt][j] = mfma16(af, ubf[j][1], a1[mt][j]);
      }
    }
#pragma unroll
    for (int mt = 0; mt < 3; ++mt)
#pragma unroll
      for (int j = 0; j < 2; ++j) {
        int node0 = (mgL * 3 + mt) * 16 + kh * 4;
        int feat = (ngL * 2 + j) * 16 + rsel;
        f32x4 v;
#pragma unroll
        for (int r = 0; r < 4; ++r) {
          float u = fmaxf(a1[mt][j][r] + bL1[j], 0.f);
          v[r] = (node0 + r < 81) ? u : 0.f;
        }
        u16x4 hi, lo;
        split4(v, hi, lo);
        int base = (node0 >> 3) * 2048 + feat * 16 + (node0 & 7) * 2;
        *(u16x4*)(lds + HB + base) = hi;
        *(u16x4*)(lds + HB + 24576 + base) = lo;
      }
  }

  u16x8 wo[4][2];                        // Wout frags, filled at l==5

  // ---- GCN layers 2..6 ----
#pragma unroll 1
  for (int l = 1; l <= 5; ++l) {
    __syncthreads();                     // hbuf ready; gbuf free
    float bw[2];
#pragma unroll
    for (int j = 0; j < 2; ++j) bw[j] = bl[l * 128 + (ngW * 2 + j) * 16 + rsel];

    // agg: g^T = h^T (A+I)   (A exact, h hi/lo -> 2 products)
    f32x4 ag[2][3];
#pragma unroll
    for (int mt = 0; mt < 2; ++mt)
#pragma unroll
      for (int j = 0; j < 3; ++j) ag[mt][j] = f32x4{0.f, 0.f, 0.f, 0.f};
#pragma unroll
    for (int ks = 0; ks < 3; ++ks) {
      u16x8 ah[2], al2[2];
#pragma unroll
      for (int mt = 0; mt < 2; ++mt) {
        int feat = (mg2 * 2 + mt) * 16 + rsel;
        int ba = (ks * 4 + kh) * 2048 + feat * 16;
        ah[mt] = *(const u16x8*)(lds + HB + ba);
        al2[mt] = *(const u16x8*)(lds + HB + 24576 + ba);
      }
#pragma unroll
      for (int mt = 0; mt < 2; ++mt)
#pragma unroll
        for (int j = 0; j < 3; ++j) {
          ag[mt][j] = mfma16(ah[mt], abf[j][ks], ag[mt][j]);
          ag[mt][j] = mfma16(al2[mt], abf[j][ks], ag[mt][j]);
        }
    }
    // agg epi -> gbuf [node][feat], split, no bias/relu
#pragma unroll
    for (int mt = 0; mt < 2; ++mt)
#pragma unroll
      for (int j = 0; j < 3; ++j) {
        int node = (ng2 * 3 + j) * 16 + rsel;
        int f0 = (mg2 * 2 + mt) * 16 + kh * 4;
        u16x4 hi, lo;
        split4(ag[mt][j], hi, lo);
        int base = (f0 >> 3) * 1536 + node * 16 + (f0 & 7) * 2;
        *(u16x4*)(lds + GB + base) = hi;
        *(u16x4*)(lds + GB + 24576 + base) = lo;
      }
    __syncthreads();                     // gbuf ready; hbuf free

    if (l < 5) {
      // W-GEMM: h' = g (W/21): 3-product hi/lo
      f32x4 wc[3][2];
#pragma unroll
      for (int mt = 0; mt < 3; ++mt)
#pragma unroll
        for (int j = 0; j < 2; ++j) wc[mt][j] = f32x4{0.f, 0.f, 0.f, 0.f};
#pragma unroll
      for (int ks = 0; ks < 4; ++ks) {
        u16x8 gh[3], gl[3];
#pragma unroll
        for (int mt = 0; mt < 3; ++mt) {
          int node = (mgW * 3 + mt) * 16 + rsel;
          int ba = (ks * 4 + kh) * 1536 + node * 16;
          gh[mt] = *(const u16x8*)(lds + GB + ba);
          gl[mt] = *(const u16x8*)(lds + GB + 24576 + ba);
        }
#pragma unroll
        for (int mt = 0; mt < 3; ++mt)
#pragma unroll
          for (int j = 0; j < 2; ++j) {
            wc[mt][j] = mfma16(gh[mt], wbf[j][ks][0], wc[mt][j]);
            wc[mt][j] = mfma16(gh[mt], wbf[j][ks][1], wc[mt][j]);
            wc[mt][j] = mfma16(gl[mt], wbf[j][ks][0], wc[mt][j]);
          }
      }
      // prefetch next layer's W frags (flip tiles when next layer is l==5)
      loadWBall(l, (l == 4) ? mg2 * 2 : ngW * 2);
      // epi: bias+relu+mask -> hbuf [feat][node]
#pragma unroll
      for (int mt = 0; mt < 3; ++mt)
#pragma unroll
        for (int j = 0; j < 2; ++j) {
          int node0 = (mgW * 3 + mt) * 16 + kh * 4;
          int feat = (ngW * 2 + j) * 16 + rsel;
          f32x4 v;
#pragma unroll
          for (int r = 0; r < 4; ++r) {
            float u = fmaxf(wc[mt][j][r] + bw[j], 0.f);
            v[r] = (node0 + r < 81) ? u : 0.f;
          }
          u16x4 hi, lo;
          split4(v, hi, lo);
          int base = (node0 >> 3) * 2048 + feat * 16 + (node0 & 7) * 2;
          *(u16x4*)(lds + HB + base) = hi;
          *(u16x4*)(lds + HB + 24576 + base) = lo;
        }
    } else {
      // flipped: h6^T = (W/21)^T g^T  -> h6 stored [node][feat] in hbuf region
      float b5[2][4];
#pragma unroll
      for (int mt = 0; mt < 2; ++mt)
#pragma unroll
        for (int r = 0; r < 4; ++r)
          b5[mt][r] = bl[5 * 128 + (mg2 * 2 + mt) * 16 + kh * 4 + r];
      f32x4 wc[2][3];
#pragma unroll
      for (int mt = 0; mt < 2; ++mt)
#pragma unroll
        for (int j = 0; j < 3; ++j) wc[mt][j] = f32x4{0.f, 0.f, 0.f, 0.f};
#pragma unroll
      for (int ks = 0; ks < 4; ++ks) {
        u16x8 gh[3], gl[3];
#pragma unroll
        for (int j = 0; j < 3; ++j) {
          int node = (ng2 * 3 + j) * 16 + rsel;
          int ba = (ks * 4 + kh) * 1536 + node * 16;
          gh[j] = *(const u16x8*)(lds + GB + ba);
          gl[j] = *(const u16x8*)(lds + GB + 24576 + ba);
        }
#pragma unroll
        for (int mt = 0; mt < 2; ++mt)
#pragma unroll
          for (int j = 0; j < 3; ++j) {
            wc[mt][j] = mfma16(wbf[mt][ks][0], gh[j], wc[mt][j]);
            wc[mt][j] = mfma16(wbf[mt][ks][0], gl[j], wc[mt][j]);
            wc[mt][j] = mfma16(wbf[mt][ks][1], gh[j], wc[mt][j]);
          }
      }
      // load Wout frags now (latency hidden under epi + barrier)
#pragma unroll
      for (int ks = 0; ks < 4; ++ks)
#pragma unroll
        for (int pl = 0; pl < 2; ++pl) {
          if constexpr (PRE)
            wo[ks][pl] = *(const u16x8*)(G + OFF_WOUT + (ks * 2 + pl) * 1024 + lane * 16);
          else {
            int col = rsel, k0 = ks * 32 + kh * 8;
            u16x8 r;
#pragma unroll
            for (int i = 0; i < 8; ++i) {
              float v = (col < 9) ? Wout[(k0 + i) * 9 + col] : 0.f;
              unsigned short h = f2bf(v);
              r[i] = pl ? f2bf(v - bf2f(h)) : h;
            }
            wo[ks][pl] = r;
          }
        }
      // epi: C row=outfeat(4 consec), col=node -> h6buf[node][feat] b64-packed
#pragma unroll
      for (int mt = 0; mt < 2; ++mt)
#pragma unroll
        for (int j = 0; j < 3; ++j) {
          int node = (ng2 * 3 + j) * 16 + rsel;
          int f0 = (mg2 * 2 + mt) * 16 + kh * 4;
          f32x4 v;
#pragma unroll
          for (int r = 0; r < 4; ++r) {
            float u = fmaxf(wc[mt][j][r] + b5[mt][r], 0.f);
            v[r] = (node < 81) ? u : 0.f;
          }
          u16x4 hi, lo;
          split4(v, hi, lo);
          int base = (f0 >> 3) * 1536 + node * 16 + (f0 & 7) * 2;
          *(u16x4*)(lds + HB + base) = hi;
          *(u16x4*)(lds + HB + 24576 + base) = lo;
        }
    }
  }

  __syncthreads();
  // ---- output GEMM: logits = h6 @ Wout + bout (waves 0..5, 1 tile each) ----
  if (w < 6) {
    f32x4 oc = f32x4{0.f, 0.f, 0.f, 0.f};
#pragma unroll
    for (int ks = 0; ks < 4; ++ks) {
      int node = w * 16 + rsel;
      int ba = (ks * 4 + kh) * 1536 + node * 16;
      u16x8 hh = *(const u16x8*)(lds + HB + ba);
      u16x8 hl = *(const u16x8*)(lds + HB + 24576 + ba);
      oc = mfma16(hh, wo[ks][0], oc);
      oc = mfma16(hh, wo[ks][1], oc);
      oc = mfma16(hl, wo[ks][0], oc);
    }
    int colo = rsel;
    if (colo < 9) {
      float bo = bout[colo];
#pragma unroll
      for (int r = 0; r < 4; ++r) {
        int node = w * 16 + kh * 4 + r;
        if (node < 81) out[b * 729 + node * 9 + colo] = oc[r] + bo;
      }
    }
  }
}

// ------------------------------- launcher ------------------------------------
extern "C" void kernel_launch(void* const* d_in, const int* in_sizes, int n_in,
                              void* d_out, int out_size, void* d_ws, size_t ws_size,
                              hipStream_t stream) {
  const int*   x    = (const int*)d_in[0];
  const float* Win  = (const float*)d_in[1];
  const float* bin  = (const float*)d_in[2];
  const float* Wl   = (const float*)d_in[3];
  const float* blay = (const float*)d_in[4];
  const float* Wout = (const float*)d_in[5];
  const float* bout = (const float*)d_in[6];
  float* out = (float*)d_out;
  int nB = in_sizes[0] / 81;

  bool pre = ws_size >= WS_NEED;
  gnn_setup<<<1, 256, 0, stream>>>(Win, bin, Wl, (float*)d_ws);     // U -> ws+0
  if (pre)
    gnn_pack<<<362, 64, 0, stream>>>(Wl, Wout, (const float*)d_ws, (char*)d_ws);

  if (pre) {
    hipFuncSetAttribute((const void*)gnn_main<true>,
                        hipFuncAttributeMaxDynamicSharedMemorySize, LDS_SZ);
    gnn_main<true><<<nB, 512, LDS_SZ, stream>>>(x, Wl, blay, Wout, bout,
                                                (const float*)d_ws, out, nB);
  } else {
    hipFuncSetAttribute((const void*)gnn_main<false>,
                        hipFuncAttributeMaxDynamicSharedMemorySize, LDS_SZ);
    gnn_main<false><<<nB, 512, LDS_SZ, stream>>>(x, Wl, blay, Wout, bout,
                                                 (const float*)d_ws, out, nB);
  }
}

// Round 3
// 932.933 us; speedup vs baseline: 1.1015x; 1.0008x over previous
//
#include <hip/hip_runtime.h>

// ---------------------------------------------------------------------------
// Sudoku GCN, fully fused, MFMA-everything.
//   h_{l+1} = relu( (A+I) h_l * (W_l/21) + b_l ),  A+I exact 0/1 in bf16.
// Orientation ping-pong (no transposed reads, all epi writes b64-packed):
//   hbuf = h^T [feat][node] (chunk-major), gbuf = g [node][feat] (chunk-major)
//   agg : g^T = h^T (A+I)     reads hbuf rows, writes gbuf packed
//   gemm: h'  = g (W/21)      reads gbuf rows, writes hbuf packed
//   l=6 : h6^T = W^T g^T      writes h6 as [node][feat] for the output GEMM
// Layer 1 collapsed: h1 = relu(Cnt @ U + b1), U = relu(Win+bin)@W1/21.
// Weights: setup kernels pre-split (bf16 hi/lo, 3-product GEMM) into
// per-wave-coalesced 1KB fragment blobs in d_ws; loaded global->VGPR.
// ---------------------------------------------------------------------------

typedef short          s16x8 __attribute__((ext_vector_type(8)));
typedef unsigned short u16x8 __attribute__((ext_vector_type(8)));
typedef unsigned short u16x4 __attribute__((ext_vector_type(4)));
typedef float          f32x4 __attribute__((ext_vector_type(4)));

#define HB   0        // hbuf: [2 pl][12 chunk][128 feat][16B]  plane stride 24576
#define GB   49152    // gbuf: [2 pl][16 chunk][96 node][16B]   plane stride 24576
#define CNT  98304    // cnt : [4 chunk][96 node][16B] = 6144
#define XC   104448   // x cache: 81 ints
#define LDS_SZ 104832

#define OFF_WB   5120     // [l 0..4][nt 0..7][ks 0..3][pl 0..1] x 1024B
#define OFF_AB   332800   // [nt 0..5][ks 0..2] x 1024B  (A+I, hi only, exact)
#define OFF_UB   351232   // [nt 0..7][pl] x 1024B
#define OFF_WOUT 367616   // [ks 0..3][pl] x 1024B
#define WS_NEED  375808

__device__ __forceinline__ unsigned short f2bf(float f) {   // RTNE f32->bf16
  unsigned u = __builtin_bit_cast(unsigned, f);
  u += 0x7FFFu + ((u >> 16) & 1u);
  return (unsigned short)(u >> 16);
}
__device__ __forceinline__ float bf2f(unsigned short h) {
  unsigned u = ((unsigned)h) << 16;
  return __builtin_bit_cast(float, u);
}
__device__ __forceinline__ f32x4 mfma16(u16x8 a, u16x8 b, f32x4 c) {
  return __builtin_amdgcn_mfma_f32_16x16x32_bf16(
      __builtin_bit_cast(s16x8, a), __builtin_bit_cast(s16x8, b), c, 0, 0, 0);
}
__device__ __forceinline__ void split4(f32x4 v, u16x4& hi, u16x4& lo) {
#pragma unroll
  for (int r = 0; r < 4; ++r) {
    unsigned short h = f2bf(v[r]);
    hi[r] = h;
    lo[r] = f2bf(v[r] - bf2f(h));
  }
}
__device__ __forceinline__ bool adjf(int r, int c) {
  if (r >= 81 || c >= 81) return false;
  int ri = r / 9, rj = r % 9, ci = c / 9, cj = c % 9;
  return ri == ci || rj == cj || (ri / 3 == ci / 3 && rj / 3 == cj / 3);
}
__device__ __forceinline__ u16x8 makeAB(int nt, int ks, int lane) {
  int col = nt * 16 + (lane & 15), k0 = ks * 32 + (lane >> 4) * 8;
  u16x8 r;
#pragma unroll
  for (int i = 0; i < 8; ++i) r[i] = adjf(k0 + i, col) ? 0x3F80 : 0;
  return r;
}

// ---------------- setup1: U[10][128] = relu(Win+bin) @ W1 / 21 (f32, ws+0) ---
extern "C" __global__ void gnn_setup(const float* __restrict__ Win,
                                     const float* __restrict__ bin,
                                     const float* __restrict__ W1,
                                     float* __restrict__ U) {
  __shared__ float V[1280];
  int t = threadIdx.x;
#pragma unroll
  for (int q = 0; q < 5; ++q) {
    int idx = t + 256 * q;
    V[idx] = fmaxf(Win[idx] + bin[idx & 127], 0.f);
  }
  __syncthreads();
#pragma unroll
  for (int p = 0; p < 5; ++p) {
    int o = t + 256 * p;
    int d = o >> 7, c = o & 127;
    float s = 0.f;
    for (int f = 0; f < 128; ++f) s += V[d * 128 + f] * W1[f * 128 + c];
    U[o] = s * (1.f / 21.f);
  }
}

// ---------------- setup2: pack all B/A fragment blobs into ws ----------------
extern "C" __global__ void gnn_pack(const float* __restrict__ Wl,
                                    const float* __restrict__ Wout,
                                    const float* __restrict__ Uscr,
                                    char* __restrict__ G) {
  int unit = blockIdx.x, lane = threadIdx.x;
  int rsel = lane & 15, kh = lane >> 4;
  u16x8 r;
  char* dst;
  if (unit < 320) {                       // WB: ((l*8+nt)*4+ks)*2+pl
    int pl = unit & 1, ks = (unit >> 1) & 3, nt = (unit >> 3) & 7, l = unit >> 6;
    int col = nt * 16 + rsel, k0 = ks * 32 + kh * 8;
    const float* src = Wl + (l + 1) * 16384 + k0 * 128 + col;
#pragma unroll
    for (int i = 0; i < 8; ++i) {
      float v = src[i * 128] * (1.f / 21.f);
      unsigned short h = f2bf(v);
      r[i] = pl ? f2bf(v - bf2f(h)) : h;
    }
    dst = G + OFF_WB + unit * 1024 + lane * 16;
  } else if (unit < 338) {                // AB: nt*3+ks
    int u2 = unit - 320, nt = u2 / 3, ks = u2 % 3;
    r = makeAB(nt, ks, lane);
    dst = G + OFF_AB + u2 * 1024 + lane * 16;
  } else if (unit < 354) {                // UB: nt*2+pl
    int u2 = unit - 338, nt = u2 >> 1, pl = u2 & 1;
    int col = nt * 16 + rsel;
#pragma unroll
    for (int i = 0; i < 8; ++i) {
      int k = kh * 8 + i;
      float v = (k < 10) ? Uscr[k * 128 + col] : 0.f;
      unsigned short h = f2bf(v);
      r[i] = pl ? f2bf(v - bf2f(h)) : h;
    }
    dst = G + OFF_UB + u2 * 1024 + lane * 16;
  } else {                                // WOUT: ks*2+pl
    int u2 = unit - 354, ks = u2 >> 1, pl = u2 & 1;
    int col = rsel, k0 = ks * 32 + kh * 8;
#pragma unroll
    for (int i = 0; i < 8; ++i) {
      float v = (col < 9) ? Wout[(k0 + i) * 9 + col] : 0.f;
      unsigned short h = f2bf(v);
      r[i] = pl ? f2bf(v - bf2f(h)) : h;
    }
    dst = G + OFF_WOUT + u2 * 1024 + lane * 16;
  }
  *(u16x8*)dst = r;
}

// --------------------------------- main -------------------------------------
template <bool PRE>
__global__ void __launch_bounds__(512, 1)
gnn_main(const int* __restrict__ x, const float* __restrict__ Wl,
         const float* __restrict__ bl, const float* __restrict__ Wout,
         const float* __restrict__ bout, const float* __restrict__ ws,
         float* __restrict__ out, int nB) {
  extern __shared__ char lds[];
  const int t = threadIdx.x, lane = t & 63, w = t >> 6;
  const int rsel = lane & 15, kh = lane >> 4;
  const char* G = (const char*)ws;
  const int b = blockIdx.x;

  // wave->tile mappings
  const int mgL = w & 1, ngL = w >> 1;   // L1 : m(node) 3 tiles, n(feat) 2
  const int mg2 = w >> 1, ng2 = w & 1;   // agg + flipped: m 2 tiles, n 3
  const int mgW = w & 1, ngW = w >> 1;   // W   : m(node) 3 tiles, n(feat) 2

  // ---- persistent operand fragments (global -> VGPR) ----
  u16x8 abf[3][3];                       // A+I B-frags (exact, hi only)
#pragma unroll
  for (int j = 0; j < 3; ++j)
#pragma unroll
    for (int ks = 0; ks < 3; ++ks) {
      if constexpr (PRE)
        abf[j][ks] = *(const u16x8*)(G + OFF_AB + ((ng2 * 3 + j) * 3 + ks) * 1024 + lane * 16);
      else
        abf[j][ks] = makeAB(ng2 * 3 + j, ks, lane);
    }
  u16x8 ubf[2][2];                       // U B-frags [j][pl]
#pragma unroll
  for (int j = 0; j < 2; ++j)
#pragma unroll
    for (int pl = 0; pl < 2; ++pl) {
      if constexpr (PRE)
        ubf[j][pl] = *(const u16x8*)(G + OFF_UB + (((ngL * 2 + j) * 2) + pl) * 1024 + lane * 16);
      else {
        int col = (ngL * 2 + j) * 16 + rsel;
        u16x8 r;
#pragma unroll
        for (int i = 0; i < 8; ++i) {
          int k = kh * 8 + i;
          float v = (k < 10) ? ws[k * 128 + col] : 0.f;
          unsigned short h = f2bf(v);
          r[i] = pl ? f2bf(v - bf2f(h)) : h;
        }
        ubf[j][pl] = r;
      }
    }
  u16x8 wbf[2][4][2];                    // W frags [j][ks][pl]
  auto loadWBall = [&](int blob, int ntbase) {
#pragma unroll
    for (int j = 0; j < 2; ++j)
#pragma unroll
      for (int ks = 0; ks < 4; ++ks)
#pragma unroll
        for (int pl = 0; pl < 2; ++pl) {
          if constexpr (PRE) {
            wbf[j][ks][pl] = *(const u16x8*)(
                G + OFF_WB + ((((blob * 8 + (ntbase + j)) * 4 + ks) * 2 + pl) << 10) + lane * 16);
          } else {
            int colw = (ntbase + j) * 16 + rsel, k0 = ks * 32 + kh * 8;
            const float* src = Wl + (blob + 1) * 16384 + k0 * 128 + colw;
            u16x8 r;
#pragma unroll
            for (int i = 0; i < 8; ++i) {
              float v = src[i * 128] * (1.f / 21.f);
              unsigned short h = f2bf(v);
              r[i] = pl ? f2bf(v - bf2f(h)) : h;
            }
            wbf[j][ks][pl] = r;
          }
        }
  };
  loadWBall(0, ngW * 2);                 // layer-1 GCN weights (blob 0)

  float bL1[2];
#pragma unroll
  for (int j = 0; j < 2; ++j) bL1[j] = bl[(ngL * 2 + j) * 16 + rsel];

  // ---- x cache + digit counts -> cntbuf ----
  if (t < 81) ((int*)(lds + XC))[t] = x[b * 81 + t];
  __syncthreads();
  if (t < 96) {
    unsigned short cnt[16];
#pragma unroll
    for (int d = 0; d < 16; ++d) cnt[d] = 0;
    if (t < 81) {
      const int* xs = (const int*)(lds + XC);
      int n = t, i = n / 9, j = n - 9 * i;
      int bi = (i / 3) * 3, bj = (j / 3) * 3;
      int rv[9], cv[9], bv[9], rb3[3], cb3[3];
#pragma unroll
      for (int k = 0; k < 9; ++k) rv[k] = xs[i * 9 + k];
#pragma unroll
      for (int k = 0; k < 9; ++k) cv[k] = xs[k * 9 + j];
#pragma unroll
      for (int r2 = 0; r2 < 3; ++r2)
#pragma unroll
        for (int c2 = 0; c2 < 3; ++c2) bv[r2 * 3 + c2] = xs[(bi + r2) * 9 + (bj + c2)];
#pragma unroll
      for (int k = 0; k < 3; ++k) rb3[k] = xs[i * 9 + bj + k];
#pragma unroll
      for (int k = 0; k < 3; ++k) cb3[k] = xs[(bi + k) * 9 + j];
#pragma unroll
      for (int d = 0; d < 10; ++d) {
        int c = 0;
#pragma unroll
        for (int k = 0; k < 9; ++k) c += (rv[k] == d) + (cv[k] == d) + (bv[k] == d);
#pragma unroll
        for (int k = 0; k < 3; ++k) c -= (rb3[k] == d) + (cb3[k] == d);
        cnt[d] = f2bf((float)c);         // integers <=21: exact in bf16
      }
    }
    u16x8 c0, c1, z;
#pragma unroll
    for (int e = 0; e < 8; ++e) { c0[e] = cnt[e]; c1[e] = cnt[8 + e]; z[e] = 0; }
    *(u16x8*)(lds + CNT + 0 * 1536 + t * 16) = c0;
    *(u16x8*)(lds + CNT + 1 * 1536 + t * 16) = c1;
    *(u16x8*)(lds + CNT + 2 * 1536 + t * 16) = z;
    *(u16x8*)(lds + CNT + 3 * 1536 + t * 16) = z;
  }
  __syncthreads();

  // ---- L1 GEMM: h1 = relu(Cnt @ U + b1) -> hbuf [feat][node] -----
  {
    f32x4 a1[3][2];
#pragma unroll
    for (int mt = 0; mt < 3; ++mt)
#pragma unroll
      for (int j = 0; j < 2; ++j) a1[mt][j] = f32x4{0.f, 0.f, 0.f, 0.f};
#pragma unroll
    for (int mt = 0; mt < 3; ++mt) {
      int node = (mgL * 3 + mt) * 16 + rsel;
      u16x8 af = *(const u16x8*)(lds + CNT + kh * 1536 + node * 16);
#pragma unroll
      for (int j = 0; j < 2; ++j) {
        a1[mt][j] = mfma16(af, ubf[j][0], a1[mt][j]);
        a1[mt][j] = mfma16(af, ubf[j][1], a1[mt][j]);
      }
    }
#pragma unroll
    for (int mt = 0; mt < 3; ++mt)
#pragma unroll
      for (int j = 0; j < 2; ++j) {
        int node0 = (mgL * 3 + mt) * 16 + kh * 4;
        int feat = (ngL * 2 + j) * 16 + rsel;
        f32x4 v;
#pragma unroll
        for (int r = 0; r < 4; ++r) {
          float u = fmaxf(a1[mt][j][r] + bL1[j], 0.f);
          v[r] = (node0 + r < 81) ? u : 0.f;
        }
        u16x4 hi, lo;
        split4(v, hi, lo);
        int base = (node0 >> 3) * 2048 + feat * 16 + (node0 & 7) * 2;
        *(u16x4*)(lds + HB + base) = hi;
        *(u16x4*)(lds + HB + 24576 + base) = lo;
      }
  }

  u16x8 wo[4][2];                        // Wout frags, filled at l==5

  // ---- GCN layers 2..6 ----
#pragma unroll 1
  for (int l = 1; l <= 5; ++l) {
    __syncthreads();                     // hbuf ready; gbuf free
    float bw[2];
#pragma unroll
    for (int j = 0; j < 2; ++j) bw[j] = bl[l * 128 + (ngW * 2 + j) * 16 + rsel];

    // agg: g^T = h^T (A+I)   (A exact, h hi/lo -> 2 products)
    f32x4 ag[2][3];
#pragma unroll
    for (int mt = 0; mt < 2; ++mt)
#pragma unroll
      for (int j = 0; j < 3; ++j) ag[mt][j] = f32x4{0.f, 0.f, 0.f, 0.f};
#pragma unroll
    for (int ks = 0; ks < 3; ++ks) {
      u16x8 ah[2], al2[2];
#pragma unroll
      for (int mt = 0; mt < 2; ++mt) {
        int feat = (mg2 * 2 + mt) * 16 + rsel;
        int ba = (ks * 4 + kh) * 2048 + feat * 16;
        ah[mt] = *(const u16x8*)(lds + HB + ba);
        al2[mt] = *(const u16x8*)(lds + HB + 24576 + ba);
      }
#pragma unroll
      for (int mt = 0; mt < 2; ++mt)
#pragma unroll
        for (int j = 0; j < 3; ++j) {
          ag[mt][j] = mfma16(ah[mt], abf[j][ks], ag[mt][j]);
          ag[mt][j] = mfma16(al2[mt], abf[j][ks], ag[mt][j]);
        }
    }
    // agg epi -> gbuf [node][feat], split, no bias/relu
#pragma unroll
    for (int mt = 0; mt < 2; ++mt)
#pragma unroll
      for (int j = 0; j < 3; ++j) {
        int node = (ng2 * 3 + j) * 16 + rsel;
        int f0 = (mg2 * 2 + mt) * 16 + kh * 4;
        u16x4 hi, lo;
        split4(ag[mt][j], hi, lo);
        int base = (f0 >> 3) * 1536 + node * 16 + (f0 & 7) * 2;
        *(u16x4*)(lds + GB + base) = hi;
        *(u16x4*)(lds + GB + 24576 + base) = lo;
      }
    __syncthreads();                     // gbuf ready; hbuf free

    if (l < 5) {
      // W-GEMM: h' = g (W/21): 3-product hi/lo
      f32x4 wc[3][2];
#pragma unroll
      for (int mt = 0; mt < 3; ++mt)
#pragma unroll
        for (int j = 0; j < 2; ++j) wc[mt][j] = f32x4{0.f, 0.f, 0.f, 0.f};
#pragma unroll
      for (int ks = 0; ks < 4; ++ks) {
        u16x8 gh[3], gl[3];
#pragma unroll
        for (int mt = 0; mt < 3; ++mt) {
          int node = (mgW * 3 + mt) * 16 + rsel;
          int ba = (ks * 4 + kh) * 1536 + node * 16;
          gh[mt] = *(const u16x8*)(lds + GB + ba);
          gl[mt] = *(const u16x8*)(lds + GB + 24576 + ba);
        }
#pragma unroll
        for (int mt = 0; mt < 3; ++mt)
#pragma unroll
          for (int j = 0; j < 2; ++j) {
            wc[mt][j] = mfma16(gh[mt], wbf[j][ks][0], wc[mt][j]);
            wc[mt][j] = mfma16(gh[mt], wbf[j][ks][1], wc[mt][j]);
            wc[mt][j] = mfma16(gl[mt], wbf[j][ks][0], wc[mt][j]);
          }
      }
      // prefetch next layer's W frags (flip tiles when next layer is l==5)
      loadWBall(l, (l == 4) ? mg2 * 2 : ngW * 2);
      // epi: bias+relu+mask -> hbuf [feat][node]
#pragma unroll
      for (int mt = 0; mt < 3; ++mt)
#pragma unroll
        for (int j = 0; j < 2; ++j) {
          int node0 = (mgW * 3 + mt) * 16 + kh * 4;
          int feat = (ngW * 2 + j) * 16 + rsel;
          f32x4 v;
#pragma unroll
          for (int r = 0; r < 4; ++r) {
            float u = fmaxf(wc[mt][j][r] + bw[j], 0.f);
            v[r] = (node0 + r < 81) ? u : 0.f;
          }
          u16x4 hi, lo;
          split4(v, hi, lo);
          int base = (node0 >> 3) * 2048 + feat * 16 + (node0 & 7) * 2;
          *(u16x4*)(lds + HB + base) = hi;
          *(u16x4*)(lds + HB + 24576 + base) = lo;
        }
    } else {
      // flipped: h6^T = (W/21)^T g^T  -> h6 stored [node][feat] in hbuf region
      float b5[2][4];
#pragma unroll
      for (int mt = 0; mt < 2; ++mt)
#pragma unroll
        for (int r = 0; r < 4; ++r)
          b5[mt][r] = bl[5 * 128 + (mg2 * 2 + mt) * 16 + kh * 4 + r];
      f32x4 wc[2][3];
#pragma unroll
      for (int mt = 0; mt < 2; ++mt)
#pragma unroll
        for (int j = 0; j < 3; ++j) wc[mt][j] = f32x4{0.f, 0.f, 0.f, 0.f};
#pragma unroll
      for (int ks = 0; ks < 4; ++ks) {
        u16x8 gh[3], gl[3];
#pragma unroll
        for (int j = 0; j < 3; ++j) {
          int node = (ng2 * 3 + j) * 16 + rsel;
          int ba = (ks * 4 + kh) * 1536 + node * 16;
          gh[j] = *(const u16x8*)(lds + GB + ba);
          gl[j] = *(const u16x8*)(lds + GB + 24576 + ba);
        }
#pragma unroll
        for (int mt = 0; mt < 2; ++mt)
#pragma unroll
          for (int j = 0; j < 3; ++j) {
            wc[mt][j] = mfma16(wbf[mt][ks][0], gh[j], wc[mt][j]);
            wc[mt][j] = mfma16(wbf[mt][ks][0], gl[j], wc[mt][j]);
            wc[mt][j] = mfma16(wbf[mt][ks][1], gh[j], wc[mt][j]);
          }
      }
      // load Wout frags now (latency hidden under epi + barrier)
#pragma unroll
      for (int ks = 0; ks < 4; ++ks)
#pragma unroll
        for (int pl = 0; pl < 2; ++pl) {
          if constexpr (PRE)
            wo[ks][pl] = *(const u16x8*)(G + OFF_WOUT + (ks * 2 + pl) * 1024 + lane * 16);
          else {
            int col = rsel, k0 = ks * 32 + kh * 8;
            u16x8 r;
#pragma unroll
            for (int i = 0; i < 8; ++i) {
              float v = (col < 9) ? Wout[(k0 + i) * 9 + col] : 0.f;
              unsigned short h = f2bf(v);
              r[i] = pl ? f2bf(v - bf2f(h)) : h;
            }
            wo[ks][pl] = r;
          }
        }
      // epi: C row=outfeat(4 consec), col=node -> h6buf[node][feat] b64-packed
#pragma unroll
      for (int mt = 0; mt < 2; ++mt)
#pragma unroll
        for (int j = 0; j < 3; ++j) {
          int node = (ng2 * 3 + j) * 16 + rsel;
          int f0 = (mg2 * 2 + mt) * 16 + kh * 4;
          f32x4 v;
#pragma unroll
          for (int r = 0; r < 4; ++r) {
            float u = fmaxf(wc[mt][j][r] + b5[mt][r], 0.f);
            v[r] = (node < 81) ? u : 0.f;
          }
          u16x4 hi, lo;
          split4(v, hi, lo);
          int base = (f0 >> 3) * 1536 + node * 16 + (f0 & 7) * 2;
          *(u16x4*)(lds + HB + base) = hi;
          *(u16x4*)(lds + HB + 24576 + base) = lo;
        }
    }
  }

  __syncthreads();
  // ---- output GEMM: logits = h6 @ Wout + bout (waves 0..5, 1 tile each) ----
  if (w < 6) {
    f32x4 oc = f32x4{0.f, 0.f, 0.f, 0.f};
#pragma unroll
    for (int ks = 0; ks < 4; ++ks) {
      int node = w * 16 + rsel;
      int ba = (ks * 4 + kh) * 1536 + node * 16;
      u16x8 hh = *(const u16x8*)(lds + HB + ba);
      u16x8 hl = *(const u16x8*)(lds + HB + 24576 + ba);
      oc = mfma16(hh, wo[ks][0], oc);
      oc = mfma16(hh, wo[ks][1], oc);
      oc = mfma16(hl, wo[ks][0], oc);
    }
    int colo = rsel;
    if (colo < 9) {
      float bo = bout[colo];
#pragma unroll
      for (int r = 0; r < 4; ++r) {
        int node = w * 16 + kh * 4 + r;
        if (node < 81) out[b * 729 + node * 9 + colo] = oc[r] + bo;
      }
    }
  }
}

// ------------------------------- launcher ------------------------------------
extern "C" void kernel_launch(void* const* d_in, const int* in_sizes, int n_in,
                              void* d_out, int out_size, void* d_ws, size_t ws_size,
                              hipStream_t stream) {
  const int*   x    = (const int*)d_in[0];
  const float* Win  = (const float*)d_in[1];
  const float* bin  = (const float*)d_in[2];
  const float* Wl   = (const float*)d_in[3];
  const float* blay = (const float*)d_in[4];
  const float* Wout = (const float*)d_in[5];
  const float* bout = (const float*)d_in[6];
  float* out = (float*)d_out;
  int nB = in_sizes[0] / 81;

  bool pre = ws_size >= WS_NEED;
  gnn_setup<<<1, 256, 0, stream>>>(Win, bin, Wl, (float*)d_ws);     // U -> ws+0
  if (pre)
    gnn_pack<<<362, 64, 0, stream>>>(Wl, Wout, (const float*)d_ws, (char*)d_ws);

  if (pre) {
    hipFuncSetAttribute((const void*)gnn_main<true>,
                        hipFuncAttributeMaxDynamicSharedMemorySize, LDS_SZ);
    gnn_main<true><<<nB, 512, LDS_SZ, stream>>>(x, Wl, blay, Wout, bout,
                                                (const float*)d_ws, out, nB);
  } else {
    hipFuncSetAttribute((const void*)gnn_main<false>,
                        hipFuncAttributeMaxDynamicSharedMemorySize, LDS_SZ);
    gnn_main<false><<<nB, 512, LDS_SZ, stream>>>(x, Wl, blay, Wout, bout,
                                                 (const float*)d_ws, out, nB);
  }
}

// Round 4
// 733.452 us; speedup vs baseline: 1.4011x; 1.2720x over previous
//
#include <hip/hip_runtime.h>

// ---------------------------------------------------------------------------
// Sudoku GCN, fully fused, MFMA-everything.
//   h_{l+1} = relu( (A+I) h_l * (W_l/21) + b_l ),  A+I exact 0/1 in bf16.
// Orientation ping-pong (no transposed reads, all epi writes b64-packed):
//   hbuf = h^T [feat][node] (chunk-major), gbuf = g [node][feat] (chunk-major)
//   agg : g^T = h^T (A+I)     reads hbuf rows, writes gbuf packed
//   gemm: h'  = g (W/21)      reads gbuf rows, writes hbuf packed
//   l=6 : h6^T = W^T g^T      writes h6 as [node][feat] for the output GEMM
// Layer 1 collapsed: h1 = relu(Cnt @ U + b1), U = relu(Win+bin)@W1/21.
// Weights: setup kernels pre-split (bf16 hi/lo, 3-product GEMM) into
// per-wave-coalesced 1KB fragment blobs in d_ws; loaded global->VGPR.
// R4: spill fix — launch_bounds(512,2) (256-VGPR budget; LDS already limits
// us to 1 WG/CU so no occupancy cost), peel l==5 so wo[] has a tight live
// range, scope ubf/bL1 to the L1 block. (R3: 736 MB/dispatch scratch writes.)
// ---------------------------------------------------------------------------

typedef short          s16x8 __attribute__((ext_vector_type(8)));
typedef unsigned short u16x8 __attribute__((ext_vector_type(8)));
typedef unsigned short u16x4 __attribute__((ext_vector_type(4)));
typedef float          f32x4 __attribute__((ext_vector_type(4)));

#define HB   0        // hbuf: [2 pl][12 chunk][128 feat][16B]  plane stride 24576
#define GB   49152    // gbuf: [2 pl][16 chunk][96 node][16B]   plane stride 24576
#define CNT  98304    // cnt : [4 chunk][96 node][16B] = 6144
#define XC   104448   // x cache: 81 ints
#define LDS_SZ 104832

#define OFF_WB   5120     // [l 0..4][nt 0..7][ks 0..3][pl 0..1] x 1024B
#define OFF_AB   332800   // [nt 0..5][ks 0..2] x 1024B  (A+I, hi only, exact)
#define OFF_UB   351232   // [nt 0..7][pl] x 1024B
#define OFF_WOUT 367616   // [ks 0..3][pl] x 1024B
#define WS_NEED  375808

__device__ __forceinline__ unsigned short f2bf(float f) {   // RTNE f32->bf16
  unsigned u = __builtin_bit_cast(unsigned, f);
  u += 0x7FFFu + ((u >> 16) & 1u);
  return (unsigned short)(u >> 16);
}
__device__ __forceinline__ float bf2f(unsigned short h) {
  unsigned u = ((unsigned)h) << 16;
  return __builtin_bit_cast(float, u);
}
__device__ __forceinline__ f32x4 mfma16(u16x8 a, u16x8 b, f32x4 c) {
  return __builtin_amdgcn_mfma_f32_16x16x32_bf16(
      __builtin_bit_cast(s16x8, a), __builtin_bit_cast(s16x8, b), c, 0, 0, 0);
}
__device__ __forceinline__ void split4(f32x4 v, u16x4& hi, u16x4& lo) {
#pragma unroll
  for (int r = 0; r < 4; ++r) {
    unsigned short h = f2bf(v[r]);
    hi[r] = h;
    lo[r] = f2bf(v[r] - bf2f(h));
  }
}
__device__ __forceinline__ bool adjf(int r, int c) {
  if (r >= 81 || c >= 81) return false;
  int ri = r / 9, rj = r % 9, ci = c / 9, cj = c % 9;
  return ri == ci || rj == cj || (ri / 3 == ci / 3 && rj / 3 == cj / 3);
}
__device__ __forceinline__ u16x8 makeAB(int nt, int ks, int lane) {
  int col = nt * 16 + (lane & 15), k0 = ks * 32 + (lane >> 4) * 8;
  u16x8 r;
#pragma unroll
  for (int i = 0; i < 8; ++i) r[i] = adjf(k0 + i, col) ? 0x3F80 : 0;
  return r;
}

// ---------------- setup1: U[10][128] = relu(Win+bin) @ W1 / 21 (f32, ws+0) ---
extern "C" __global__ void gnn_setup(const float* __restrict__ Win,
                                     const float* __restrict__ bin,
                                     const float* __restrict__ W1,
                                     float* __restrict__ U) {
  __shared__ float V[1280];
  int t = threadIdx.x;
#pragma unroll
  for (int q = 0; q < 5; ++q) {
    int idx = t + 256 * q;
    V[idx] = fmaxf(Win[idx] + bin[idx & 127], 0.f);
  }
  __syncthreads();
#pragma unroll
  for (int p = 0; p < 5; ++p) {
    int o = t + 256 * p;
    int d = o >> 7, c = o & 127;
    float s = 0.f;
    for (int f = 0; f < 128; ++f) s += V[d * 128 + f] * W1[f * 128 + c];
    U[o] = s * (1.f / 21.f);
  }
}

// ---------------- setup2: pack all B/A fragment blobs into ws ----------------
extern "C" __global__ void gnn_pack(const float* __restrict__ Wl,
                                    const float* __restrict__ Wout,
                                    const float* __restrict__ Uscr,
                                    char* __restrict__ G) {
  int unit = blockIdx.x, lane = threadIdx.x;
  int rsel = lane & 15, kh = lane >> 4;
  u16x8 r;
  char* dst;
  if (unit < 320) {                       // WB: ((l*8+nt)*4+ks)*2+pl
    int pl = unit & 1, ks = (unit >> 1) & 3, nt = (unit >> 3) & 7, l = unit >> 6;
    int col = nt * 16 + rsel, k0 = ks * 32 + kh * 8;
    const float* src = Wl + (l + 1) * 16384 + k0 * 128 + col;
#pragma unroll
    for (int i = 0; i < 8; ++i) {
      float v = src[i * 128] * (1.f / 21.f);
      unsigned short h = f2bf(v);
      r[i] = pl ? f2bf(v - bf2f(h)) : h;
    }
    dst = G + OFF_WB + unit * 1024 + lane * 16;
  } else if (unit < 338) {                // AB: nt*3+ks
    int u2 = unit - 320, nt = u2 / 3, ks = u2 % 3;
    r = makeAB(nt, ks, lane);
    dst = G + OFF_AB + u2 * 1024 + lane * 16;
  } else if (unit < 354) {                // UB: nt*2+pl
    int u2 = unit - 338, nt = u2 >> 1, pl = u2 & 1;
    int col = nt * 16 + rsel;
#pragma unroll
    for (int i = 0; i < 8; ++i) {
      int k = kh * 8 + i;
      float v = (k < 10) ? Uscr[k * 128 + col] : 0.f;
      unsigned short h = f2bf(v);
      r[i] = pl ? f2bf(v - bf2f(h)) : h;
    }
    dst = G + OFF_UB + u2 * 1024 + lane * 16;
  } else {                                // WOUT: ks*2+pl
    int u2 = unit - 354, ks = u2 >> 1, pl = u2 & 1;
    int col = rsel, k0 = ks * 32 + kh * 8;
#pragma unroll
    for (int i = 0; i < 8; ++i) {
      float v = (col < 9) ? Wout[(k0 + i) * 9 + col] : 0.f;
      unsigned short h = f2bf(v);
      r[i] = pl ? f2bf(v - bf2f(h)) : h;
    }
    dst = G + OFF_WOUT + u2 * 1024 + lane * 16;
  }
  *(u16x8*)dst = r;
}

// --------------------------------- main -------------------------------------
template <bool PRE>
__global__ void __launch_bounds__(512, 2)
gnn_main(const int* __restrict__ x, const float* __restrict__ Wl,
         const float* __restrict__ bl, const float* __restrict__ Wout,
         const float* __restrict__ bout, const float* __restrict__ ws,
         float* __restrict__ out, int nB) {
  extern __shared__ char lds[];
  const int t = threadIdx.x, lane = t & 63, w = t >> 6;
  const int rsel = lane & 15, kh = lane >> 4;
  const char* G = (const char*)ws;
  const int b = blockIdx.x;

  // wave->tile mappings
  const int mgL = w & 1, ngL = w >> 1;   // L1 : m(node) 3 tiles, n(feat) 2
  const int mg2 = w >> 1, ng2 = w & 1;   // agg + flipped: m 2 tiles, n 3
  const int mgW = w & 1, ngW = w >> 1;   // W   : m(node) 3 tiles, n(feat) 2

  // ---- persistent operand fragments (global -> VGPR) ----
  u16x8 abf[3][3];                       // A+I B-frags (exact, hi only)
#pragma unroll
  for (int j = 0; j < 3; ++j)
#pragma unroll
    for (int ks = 0; ks < 3; ++ks) {
      if constexpr (PRE)
        abf[j][ks] = *(const u16x8*)(G + OFF_AB + ((ng2 * 3 + j) * 3 + ks) * 1024 + lane * 16);
      else
        abf[j][ks] = makeAB(ng2 * 3 + j, ks, lane);
    }
  u16x8 wbf[2][4][2];                    // W frags [j][ks][pl]
  auto loadWBall = [&](int blob, int ntbase) {
#pragma unroll
    for (int j = 0; j < 2; ++j)
#pragma unroll
      for (int ks = 0; ks < 4; ++ks)
#pragma unroll
        for (int pl = 0; pl < 2; ++pl) {
          if constexpr (PRE) {
            wbf[j][ks][pl] = *(const u16x8*)(
                G + OFF_WB + ((((blob * 8 + (ntbase + j)) * 4 + ks) * 2 + pl) << 10) + lane * 16);
          } else {
            int colw = (ntbase + j) * 16 + rsel, k0 = ks * 32 + kh * 8;
            const float* src = Wl + (blob + 1) * 16384 + k0 * 128 + colw;
            u16x8 r;
#pragma unroll
            for (int i = 0; i < 8; ++i) {
              float v = src[i * 128] * (1.f / 21.f);
              unsigned short h = f2bf(v);
              r[i] = pl ? f2bf(v - bf2f(h)) : h;
            }
            wbf[j][ks][pl] = r;
          }
        }
  };
  loadWBall(0, ngW * 2);                 // layer-1 GCN weights (blob 0)

  // ---- x cache + digit counts -> cntbuf ----
  if (t < 81) ((int*)(lds + XC))[t] = x[b * 81 + t];
  __syncthreads();
  if (t < 96) {
    unsigned short cnt[16];
#pragma unroll
    for (int d = 0; d < 16; ++d) cnt[d] = 0;
    if (t < 81) {
      const int* xs = (const int*)(lds + XC);
      int n = t, i = n / 9, j = n - 9 * i;
      int bi = (i / 3) * 3, bj = (j / 3) * 3;
      int rv[9], cv[9], bv[9], rb3[3], cb3[3];
#pragma unroll
      for (int k = 0; k < 9; ++k) rv[k] = xs[i * 9 + k];
#pragma unroll
      for (int k = 0; k < 9; ++k) cv[k] = xs[k * 9 + j];
#pragma unroll
      for (int r2 = 0; r2 < 3; ++r2)
#pragma unroll
        for (int c2 = 0; c2 < 3; ++c2) bv[r2 * 3 + c2] = xs[(bi + r2) * 9 + (bj + c2)];
#pragma unroll
      for (int k = 0; k < 3; ++k) rb3[k] = xs[i * 9 + bj + k];
#pragma unroll
      for (int k = 0; k < 3; ++k) cb3[k] = xs[(bi + k) * 9 + j];
#pragma unroll
      for (int d = 0; d < 10; ++d) {
        int c = 0;
#pragma unroll
        for (int k = 0; k < 9; ++k) c += (rv[k] == d) + (cv[k] == d) + (bv[k] == d);
#pragma unroll
        for (int k = 0; k < 3; ++k) c -= (rb3[k] == d) + (cb3[k] == d);
        cnt[d] = f2bf((float)c);         // integers <=21: exact in bf16
      }
    }
    u16x8 c0, c1, z;
#pragma unroll
    for (int e = 0; e < 8; ++e) { c0[e] = cnt[e]; c1[e] = cnt[8 + e]; z[e] = 0; }
    *(u16x8*)(lds + CNT + 0 * 1536 + t * 16) = c0;
    *(u16x8*)(lds + CNT + 1 * 1536 + t * 16) = c1;
    *(u16x8*)(lds + CNT + 2 * 1536 + t * 16) = z;
    *(u16x8*)(lds + CNT + 3 * 1536 + t * 16) = z;
  }
  __syncthreads();

  // ---- L1 GEMM: h1 = relu(Cnt @ U + b1) -> hbuf [feat][node] -----
  {
    u16x8 ubf[2][2];                     // U B-frags [j][pl] (scoped: dead after L1)
#pragma unroll
    for (int j = 0; j < 2; ++j)
#pragma unroll
      for (int pl = 0; pl < 2; ++pl) {
        if constexpr (PRE)
          ubf[j][pl] = *(const u16x8*)(G + OFF_UB + (((ngL * 2 + j) * 2) + pl) * 1024 + lane * 16);
        else {
          int col = (ngL * 2 + j) * 16 + rsel;
          u16x8 r;
#pragma unroll
          for (int i = 0; i < 8; ++i) {
            int k = kh * 8 + i;
            float v = (k < 10) ? ws[k * 128 + col] : 0.f;
            unsigned short h = f2bf(v);
            r[i] = pl ? f2bf(v - bf2f(h)) : h;
          }
          ubf[j][pl] = r;
        }
      }
    float bL1[2];
#pragma unroll
    for (int j = 0; j < 2; ++j) bL1[j] = bl[(ngL * 2 + j) * 16 + rsel];

    f32x4 a1[3][2];
#pragma unroll
    for (int mt = 0; mt < 3; ++mt)
#pragma unroll
      for (int j = 0; j < 2; ++j) a1[mt][j] = f32x4{0.f, 0.f, 0.f, 0.f};
#pragma unroll
    for (int mt = 0; mt < 3; ++mt) {
      int node = (mgL * 3 + mt) * 16 + rsel;
      u16x8 af = *(const u16x8*)(lds + CNT + kh * 1536 + node * 16);
#pragma unroll
      for (int j = 0; j < 2; ++j) {
        a1[mt][j] = mfma16(af, ubf[j][0], a1[mt][j]);
        a1[mt][j] = mfma16(af, ubf[j][1], a1[mt][j]);
      }
    }
#pragma unroll
    for (int mt = 0; mt < 3; ++mt)
#pragma unroll
      for (int j = 0; j < 2; ++j) {
        int node0 = (mgL * 3 + mt) * 16 + kh * 4;
        int feat = (ngL * 2 + j) * 16 + rsel;
        f32x4 v;
#pragma unroll
        for (int r = 0; r < 4; ++r) {
          float u = fmaxf(a1[mt][j][r] + bL1[j], 0.f);
          v[r] = (node0 + r < 81) ? u : 0.f;
        }
        u16x4 hi, lo;
        split4(v, hi, lo);
        int base = (node0 >> 3) * 2048 + feat * 16 + (node0 & 7) * 2;
        *(u16x4*)(lds + HB + base) = hi;
        *(u16x4*)(lds + HB + 24576 + base) = lo;
      }
  }

  // agg: g^T = h^T (A+I)   (A exact, h hi/lo -> 2 products); epi -> gbuf
  auto do_agg = [&]() {
    f32x4 ag[2][3];
#pragma unroll
    for (int mt = 0; mt < 2; ++mt)
#pragma unroll
      for (int j = 0; j < 3; ++j) ag[mt][j] = f32x4{0.f, 0.f, 0.f, 0.f};
#pragma unroll
    for (int ks = 0; ks < 3; ++ks) {
      u16x8 ah[2], al2[2];
#pragma unroll
      for (int mt = 0; mt < 2; ++mt) {
        int feat = (mg2 * 2 + mt) * 16 + rsel;
        int ba = (ks * 4 + kh) * 2048 + feat * 16;
        ah[mt] = *(const u16x8*)(lds + HB + ba);
        al2[mt] = *(const u16x8*)(lds + HB + 24576 + ba);
      }
#pragma unroll
      for (int mt = 0; mt < 2; ++mt)
#pragma unroll
        for (int j = 0; j < 3; ++j) {
          ag[mt][j] = mfma16(ah[mt], abf[j][ks], ag[mt][j]);
          ag[mt][j] = mfma16(al2[mt], abf[j][ks], ag[mt][j]);
        }
    }
#pragma unroll
    for (int mt = 0; mt < 2; ++mt)
#pragma unroll
      for (int j = 0; j < 3; ++j) {
        int node = (ng2 * 3 + j) * 16 + rsel;
        int f0 = (mg2 * 2 + mt) * 16 + kh * 4;
        u16x4 hi, lo;
        split4(ag[mt][j], hi, lo);
        int base = (f0 >> 3) * 1536 + node * 16 + (f0 & 7) * 2;
        *(u16x4*)(lds + GB + base) = hi;
        *(u16x4*)(lds + GB + 24576 + base) = lo;
      }
  };

  // ---- GCN layers 2..5 (uniform orientation; l==5 peeled below) ----
#pragma unroll 1
  for (int l = 1; l <= 4; ++l) {
    __syncthreads();                     // hbuf ready; gbuf free
    float bw[2];
#pragma unroll
    for (int j = 0; j < 2; ++j) bw[j] = bl[l * 128 + (ngW * 2 + j) * 16 + rsel];

    do_agg();
    __syncthreads();                     // gbuf ready; hbuf free

    // W-GEMM: h' = g (W/21): 3-product hi/lo
    f32x4 wc[3][2];
#pragma unroll
    for (int mt = 0; mt < 3; ++mt)
#pragma unroll
      for (int j = 0; j < 2; ++j) wc[mt][j] = f32x4{0.f, 0.f, 0.f, 0.f};
#pragma unroll
    for (int ks = 0; ks < 4; ++ks) {
      u16x8 gh[3], gl[3];
#pragma unroll
      for (int mt = 0; mt < 3; ++mt) {
        int node = (mgW * 3 + mt) * 16 + rsel;
        int ba = (ks * 4 + kh) * 1536 + node * 16;
        gh[mt] = *(const u16x8*)(lds + GB + ba);
        gl[mt] = *(const u16x8*)(lds + GB + 24576 + ba);
      }
#pragma unroll
      for (int mt = 0; mt < 3; ++mt)
#pragma unroll
        for (int j = 0; j < 2; ++j) {
          wc[mt][j] = mfma16(gh[mt], wbf[j][ks][0], wc[mt][j]);
          wc[mt][j] = mfma16(gh[mt], wbf[j][ks][1], wc[mt][j]);
          wc[mt][j] = mfma16(gl[mt], wbf[j][ks][0], wc[mt][j]);
        }
    }
    // prefetch next layer's W frags (flip tiles when next layer is l==5)
    loadWBall(l, (l == 4) ? mg2 * 2 : ngW * 2);
    // epi: bias+relu+mask -> hbuf [feat][node]
#pragma unroll
    for (int mt = 0; mt < 3; ++mt)
#pragma unroll
      for (int j = 0; j < 2; ++j) {
        int node0 = (mgW * 3 + mt) * 16 + kh * 4;
        int feat = (ngW * 2 + j) * 16 + rsel;
        f32x4 v;
#pragma unroll
        for (int r = 0; r < 4; ++r) {
          float u = fmaxf(wc[mt][j][r] + bw[j], 0.f);
          v[r] = (node0 + r < 81) ? u : 0.f;
        }
        u16x4 hi, lo;
        split4(v, hi, lo);
        int base = (node0 >> 3) * 2048 + feat * 16 + (node0 & 7) * 2;
        *(u16x4*)(lds + HB + base) = hi;
        *(u16x4*)(lds + HB + 24576 + base) = lo;
      }
  }

  // ---- layer 6 (l==5), peeled: agg, then flipped h6^T = (W/21)^T g^T ----
  __syncthreads();                       // hbuf ready
  do_agg();
  __syncthreads();                       // gbuf ready; hbuf free

  u16x8 wo[4][2];                        // Wout frags (tight live range)
  {
    float b5[2][4];
#pragma unroll
    for (int mt = 0; mt < 2; ++mt)
#pragma unroll
      for (int r = 0; r < 4; ++r)
        b5[mt][r] = bl[5 * 128 + (mg2 * 2 + mt) * 16 + kh * 4 + r];
    f32x4 wc[2][3];
#pragma unroll
    for (int mt = 0; mt < 2; ++mt)
#pragma unroll
      for (int j = 0; j < 3; ++j) wc[mt][j] = f32x4{0.f, 0.f, 0.f, 0.f};
#pragma unroll
    for (int ks = 0; ks < 4; ++ks) {
      u16x8 gh[3], gl[3];
#pragma unroll
      for (int j = 0; j < 3; ++j) {
        int node = (ng2 * 3 + j) * 16 + rsel;
        int ba = (ks * 4 + kh) * 1536 + node * 16;
        gh[j] = *(const u16x8*)(lds + GB + ba);
        gl[j] = *(const u16x8*)(lds + GB + 24576 + ba);
      }
#pragma unroll
      for (int mt = 0; mt < 2; ++mt)
#pragma unroll
        for (int j = 0; j < 3; ++j) {
          wc[mt][j] = mfma16(wbf[mt][ks][0], gh[j], wc[mt][j]);
          wc[mt][j] = mfma16(wbf[mt][ks][0], gl[j], wc[mt][j]);
          wc[mt][j] = mfma16(wbf[mt][ks][1], gh[j], wc[mt][j]);
        }
    }
    // load Wout frags now (latency hidden under epi + barrier)
#pragma unroll
    for (int ks = 0; ks < 4; ++ks)
#pragma unroll
      for (int pl = 0; pl < 2; ++pl) {
        if constexpr (PRE)
          wo[ks][pl] = *(const u16x8*)(G + OFF_WOUT + (ks * 2 + pl) * 1024 + lane * 16);
        else {
          int col = rsel, k0 = ks * 32 + kh * 8;
          u16x8 r;
#pragma unroll
          for (int i = 0; i < 8; ++i) {
            float v = (col < 9) ? Wout[(k0 + i) * 9 + col] : 0.f;
            unsigned short h = f2bf(v);
            r[i] = pl ? f2bf(v - bf2f(h)) : h;
          }
          wo[ks][pl] = r;
        }
      }
    // epi: C row=outfeat(4 consec), col=node -> h6buf[node][feat] b64-packed
#pragma unroll
    for (int mt = 0; mt < 2; ++mt)
#pragma unroll
      for (int j = 0; j < 3; ++j) {
        int node = (ng2 * 3 + j) * 16 + rsel;
        int f0 = (mg2 * 2 + mt) * 16 + kh * 4;
        f32x4 v;
#pragma unroll
        for (int r = 0; r < 4; ++r) {
          float u = fmaxf(wc[mt][j][r] + b5[mt][r], 0.f);
          v[r] = (node < 81) ? u : 0.f;
        }
        u16x4 hi, lo;
        split4(v, hi, lo);
        int base = (f0 >> 3) * 1536 + node * 16 + (f0 & 7) * 2;
        *(u16x4*)(lds + HB + base) = hi;
        *(u16x4*)(lds + HB + 24576 + base) = lo;
      }
  }

  __syncthreads();
  // ---- output GEMM: logits = h6 @ Wout + bout (waves 0..5, 1 tile each) ----
  if (w < 6) {
    f32x4 oc = f32x4{0.f, 0.f, 0.f, 0.f};
#pragma unroll
    for (int ks = 0; ks < 4; ++ks) {
      int node = w * 16 + rsel;
      int ba = (ks * 4 + kh) * 1536 + node * 16;
      u16x8 hh = *(const u16x8*)(lds + HB + ba);
      u16x8 hl = *(const u16x8*)(lds + HB + 24576 + ba);
      oc = mfma16(hh, wo[ks][0], oc);
      oc = mfma16(hh, wo[ks][1], oc);
      oc = mfma16(hl, wo[ks][0], oc);
    }
    int colo = rsel;
    if (colo < 9) {
      float bo = bout[colo];
#pragma unroll
      for (int r = 0; r < 4; ++r) {
        int node = w * 16 + kh * 4 + r;
        if (node < 81) out[b * 729 + node * 9 + colo] = oc[r] + bo;
      }
    }
  }
}

// ------------------------------- launcher ------------------------------------
extern "C" void kernel_launch(void* const* d_in, const int* in_sizes, int n_in,
                              void* d_out, int out_size, void* d_ws, size_t ws_size,
                              hipStream_t stream) {
  const int*   x    = (const int*)d_in[0];
  const float* Win  = (const float*)d_in[1];
  const float* bin  = (const float*)d_in[2];
  const float* Wl   = (const float*)d_in[3];
  const float* blay = (const float*)d_in[4];
  const float* Wout = (const float*)d_in[5];
  const float* bout = (const float*)d_in[6];
  float* out = (float*)d_out;
  int nB = in_sizes[0] / 81;

  bool pre = ws_size >= WS_NEED;
  gnn_setup<<<1, 256, 0, stream>>>(Win, bin, Wl, (float*)d_ws);     // U -> ws+0
  if (pre)
    gnn_pack<<<362, 64, 0, stream>>>(Wl, Wout, (const float*)d_ws, (char*)d_ws);

  if (pre) {
    hipFuncSetAttribute((const void*)gnn_main<true>,
                        hipFuncAttributeMaxDynamicSharedMemorySize, LDS_SZ);
    gnn_main<true><<<nB, 512, LDS_SZ, stream>>>(x, Wl, blay, Wout, bout,
                                                (const float*)d_ws, out, nB);
  } else {
    hipFuncSetAttribute((const void*)gnn_main<false>,
                        hipFuncAttributeMaxDynamicSharedMemorySize, LDS_SZ);
    gnn_main<false><<<nB, 512, LDS_SZ, stream>>>(x, Wl, blay, Wout, bout,
                                                 (const float*)d_ws, out, nB);
  }
}

// Round 5
// 671.396 us; speedup vs baseline: 1.5306x; 1.0924x over previous
//
#include <hip/hip_runtime.h>
#include <hip/hip_bf16.h>

// ---------------------------------------------------------------------------
// Sudoku GCN, fully fused, MFMA-everything.
//   h_{l+1} = relu( (A+I) h_l * (W_l/21) + b_l ),  A+I exact 0/1 in bf16.
// Orientation ping-pong (no transposed reads, all epi writes b64-packed):
//   hbuf = h^T [feat][node] (chunk-major), gbuf = g [node][feat] (chunk-major)
//   agg : g^T = h^T (A+I)     reads hbuf rows, writes gbuf packed
//   gemm: h'  = g (W/21)      reads gbuf rows, writes hbuf packed
//   l=6 : h6^T = W^T g^T      writes h6 as [node][feat] for the output GEMM
// Layer 1 collapsed: h1 = relu(Cnt @ U + b1), U = relu(Win+bin)@W1/21.
// R5: occupancy fix — 1024 threads (16 waves, 4/SIMD vs R4's 2/SIMD; LDS
// pins us to 1 block/CU either way). Per-wave work halved: each wave owns
// 1 feat-tile (ft=w>>1) x 3 node-tiles (ng=w&1) in EVERY phase, so wbf
// shrinks 16->8 frags (-32 VGPR) to fit the 128-VGPR cap of 4 waves/SIMD.
// f2bf via hardware v_cvt (same RTNE) to cut epilogue VALU.
// ---------------------------------------------------------------------------

typedef short          s16x8 __attribute__((ext_vector_type(8)));
typedef unsigned short u16x8 __attribute__((ext_vector_type(8)));
typedef unsigned short u16x4 __attribute__((ext_vector_type(4)));
typedef float          f32x4 __attribute__((ext_vector_type(4)));

#define HB   0        // hbuf: [2 pl][12 chunk][128 feat][16B]  plane stride 24576
#define GB   49152    // gbuf: [2 pl][16 chunk][96 node][16B]   plane stride 24576
#define CNT  98304    // cnt : [4 chunk][96 node][16B] = 6144
#define XC   104448   // x cache: 81 ints
#define LDS_SZ 104832

#define OFF_WB   5120     // [l 0..4][nt 0..7][ks 0..3][pl 0..1] x 1024B
#define OFF_AB   332800   // [nt 0..5][ks 0..2] x 1024B  (A+I, hi only, exact)
#define OFF_UB   351232   // [nt 0..7][pl] x 1024B
#define OFF_WOUT 367616   // [ks 0..3][pl] x 1024B
#define WS_NEED  375808

__device__ __forceinline__ unsigned short f2bf(float f) {   // RTNE via v_cvt
  return __builtin_bit_cast(unsigned short, __float2bfloat16(f));
}
__device__ __forceinline__ float bf2f(unsigned short h) {
  unsigned u = ((unsigned)h) << 16;
  return __builtin_bit_cast(float, u);
}
__device__ __forceinline__ f32x4 mfma16(u16x8 a, u16x8 b, f32x4 c) {
  return __builtin_amdgcn_mfma_f32_16x16x32_bf16(
      __builtin_bit_cast(s16x8, a), __builtin_bit_cast(s16x8, b), c, 0, 0, 0);
}
__device__ __forceinline__ void split4(f32x4 v, u16x4& hi, u16x4& lo) {
#pragma unroll
  for (int r = 0; r < 4; ++r) {
    unsigned short h = f2bf(v[r]);
    hi[r] = h;
    lo[r] = f2bf(v[r] - bf2f(h));
  }
}
__device__ __forceinline__ bool adjf(int r, int c) {
  if (r >= 81 || c >= 81) return false;
  int ri = r / 9, rj = r % 9, ci = c / 9, cj = c % 9;
  return ri == ci || rj == cj || (ri / 3 == ci / 3 && rj / 3 == cj / 3);
}
__device__ __forceinline__ u16x8 makeAB(int nt, int ks, int lane) {
  int col = nt * 16 + (lane & 15), k0 = ks * 32 + (lane >> 4) * 8;
  u16x8 r;
#pragma unroll
  for (int i = 0; i < 8; ++i) r[i] = adjf(k0 + i, col) ? 0x3F80 : 0;
  return r;
}

// ---------------- setup1: U[10][128] = relu(Win+bin) @ W1 / 21 (f32, ws+0) ---
extern "C" __global__ void gnn_setup(const float* __restrict__ Win,
                                     const float* __restrict__ bin,
                                     const float* __restrict__ W1,
                                     float* __restrict__ U) {
  __shared__ float V[1280];
  int t = threadIdx.x;
#pragma unroll
  for (int q = 0; q < 5; ++q) {
    int idx = t + 256 * q;
    V[idx] = fmaxf(Win[idx] + bin[idx & 127], 0.f);
  }
  __syncthreads();
#pragma unroll
  for (int p = 0; p < 5; ++p) {
    int o = t + 256 * p;
    int d = o >> 7, c = o & 127;
    float s = 0.f;
    for (int f = 0; f < 128; ++f) s += V[d * 128 + f] * W1[f * 128 + c];
    U[o] = s * (1.f / 21.f);
  }
}

// ---------------- setup2: pack all B/A fragment blobs into ws ----------------
extern "C" __global__ void gnn_pack(const float* __restrict__ Wl,
                                    const float* __restrict__ Wout,
                                    const float* __restrict__ Uscr,
                                    char* __restrict__ G) {
  int unit = blockIdx.x, lane = threadIdx.x;
  int rsel = lane & 15, kh = lane >> 4;
  u16x8 r;
  char* dst;
  if (unit < 320) {                       // WB: ((l*8+nt)*4+ks)*2+pl
    int pl = unit & 1, ks = (unit >> 1) & 3, nt = (unit >> 3) & 7, l = unit >> 6;
    int col = nt * 16 + rsel, k0 = ks * 32 + kh * 8;
    const float* src = Wl + (l + 1) * 16384 + k0 * 128 + col;
#pragma unroll
    for (int i = 0; i < 8; ++i) {
      float v = src[i * 128] * (1.f / 21.f);
      unsigned short h = f2bf(v);
      r[i] = pl ? f2bf(v - bf2f(h)) : h;
    }
    dst = G + OFF_WB + unit * 1024 + lane * 16;
  } else if (unit < 338) {                // AB: nt*3+ks
    int u2 = unit - 320, nt = u2 / 3, ks = u2 % 3;
    r = makeAB(nt, ks, lane);
    dst = G + OFF_AB + u2 * 1024 + lane * 16;
  } else if (unit < 354) {                // UB: nt*2+pl
    int u2 = unit - 338, nt = u2 >> 1, pl = u2 & 1;
    int col = nt * 16 + rsel;
#pragma unroll
    for (int i = 0; i < 8; ++i) {
      int k = kh * 8 + i;
      float v = (k < 10) ? Uscr[k * 128 + col] : 0.f;
      unsigned short h = f2bf(v);
      r[i] = pl ? f2bf(v - bf2f(h)) : h;
    }
    dst = G + OFF_UB + u2 * 1024 + lane * 16;
  } else {                                // WOUT: ks*2+pl
    int u2 = unit - 354, ks = u2 >> 1, pl = u2 & 1;
    int col = rsel, k0 = ks * 32 + kh * 8;
#pragma unroll
    for (int i = 0; i < 8; ++i) {
      float v = (col < 9) ? Wout[(k0 + i) * 9 + col] : 0.f;
      unsigned short h = f2bf(v);
      r[i] = pl ? f2bf(v - bf2f(h)) : h;
    }
    dst = G + OFF_WOUT + u2 * 1024 + lane * 16;
  }
  *(u16x8*)dst = r;
}

// --------------------------------- main -------------------------------------
template <bool PRE>
__global__ void __launch_bounds__(1024, 4)
gnn_main(const int* __restrict__ x, const float* __restrict__ Wl,
         const float* __restrict__ bl, const float* __restrict__ Wout,
         const float* __restrict__ bout, const float* __restrict__ ws,
         float* __restrict__ out, int nB) {
  extern __shared__ char lds[];
  const int t = threadIdx.x, lane = t & 63, w = t >> 6;   // w 0..15
  const int rsel = lane & 15, kh = lane >> 4;
  const char* G = (const char*)ws;
  const int b = blockIdx.x;

  // uniform wave->tile mapping for ALL phases:
  const int ft = w >> 1;                 // feat tile 0..7 (L1 n, agg m, W n, flip m)
  const int ng = w & 1;                  // node group 0..1 (3 node-tiles each)

  // ---- persistent operand fragments (global -> VGPR) ----
  u16x8 abf[3][3];                       // A+I B-frags (exact, hi only)
#pragma unroll
  for (int j = 0; j < 3; ++j)
#pragma unroll
    for (int ks = 0; ks < 3; ++ks) {
      if constexpr (PRE)
        abf[j][ks] = *(const u16x8*)(G + OFF_AB + ((ng * 3 + j) * 3 + ks) * 1024 + lane * 16);
      else
        abf[j][ks] = makeAB(ng * 3 + j, ks, lane);
    }
  u16x8 wbf[4][2];                       // W frags [ks][pl], one feat-tile (ft)
  auto loadWB = [&](int blob) {
#pragma unroll
    for (int ks = 0; ks < 4; ++ks)
#pragma unroll
      for (int pl = 0; pl < 2; ++pl) {
        if constexpr (PRE) {
          wbf[ks][pl] = *(const u16x8*)(
              G + OFF_WB + ((((blob * 8 + ft) * 4 + ks) * 2 + pl) << 10) + lane * 16);
        } else {
          int colw = ft * 16 + rsel, k0 = ks * 32 + kh * 8;
          const float* src = Wl + (blob + 1) * 16384 + k0 * 128 + colw;
          u16x8 r;
#pragma unroll
          for (int i = 0; i < 8; ++i) {
            float v = src[i * 128] * (1.f / 21.f);
            unsigned short h = f2bf(v);
            r[i] = pl ? f2bf(v - bf2f(h)) : h;
          }
          wbf[ks][pl] = r;
        }
      }
  };
  loadWB(0);                             // layer-2 GCN weights (blob 0)

  // ---- x cache + digit counts -> cntbuf ----
  if (t < 81) ((int*)(lds + XC))[t] = x[b * 81 + t];
  __syncthreads();
  if (t < 96) {
    unsigned short cnt[16];
#pragma unroll
    for (int d = 0; d < 16; ++d) cnt[d] = 0;
    if (t < 81) {
      const int* xs = (const int*)(lds + XC);
      int n = t, i = n / 9, j = n - 9 * i;
      int bi = (i / 3) * 3, bj = (j / 3) * 3;
      int rv[9], cv[9], bv[9], rb3[3], cb3[3];
#pragma unroll
      for (int k = 0; k < 9; ++k) rv[k] = xs[i * 9 + k];
#pragma unroll
      for (int k = 0; k < 9; ++k) cv[k] = xs[k * 9 + j];
#pragma unroll
      for (int r2 = 0; r2 < 3; ++r2)
#pragma unroll
        for (int c2 = 0; c2 < 3; ++c2) bv[r2 * 3 + c2] = xs[(bi + r2) * 9 + (bj + c2)];
#pragma unroll
      for (int k = 0; k < 3; ++k) rb3[k] = xs[i * 9 + bj + k];
#pragma unroll
      for (int k = 0; k < 3; ++k) cb3[k] = xs[(bi + k) * 9 + j];
#pragma unroll
      for (int d = 0; d < 10; ++d) {
        int c = 0;
#pragma unroll
        for (int k = 0; k < 9; ++k) c += (rv[k] == d) + (cv[k] == d) + (bv[k] == d);
#pragma unroll
        for (int k = 0; k < 3; ++k) c -= (rb3[k] == d) + (cb3[k] == d);
        cnt[d] = f2bf((float)c);         // integers <=21: exact in bf16
      }
    }
    u16x8 c0, c1, z;
#pragma unroll
    for (int e = 0; e < 8; ++e) { c0[e] = cnt[e]; c1[e] = cnt[8 + e]; z[e] = 0; }
    *(u16x8*)(lds + CNT + 0 * 1536 + t * 16) = c0;
    *(u16x8*)(lds + CNT + 1 * 1536 + t * 16) = c1;
    *(u16x8*)(lds + CNT + 2 * 1536 + t * 16) = z;
    *(u16x8*)(lds + CNT + 3 * 1536 + t * 16) = z;
  }
  __syncthreads();

  // ---- L1 GEMM: h1 = relu(Cnt @ U + b1) -> hbuf [feat][node] -----
  {
    u16x8 ubf[2];                        // U B-frags [pl] (dead after L1)
#pragma unroll
    for (int pl = 0; pl < 2; ++pl) {
      if constexpr (PRE)
        ubf[pl] = *(const u16x8*)(G + OFF_UB + (ft * 2 + pl) * 1024 + lane * 16);
      else {
        int col = ft * 16 + rsel;
        u16x8 r;
#pragma unroll
        for (int i = 0; i < 8; ++i) {
          int k = kh * 8 + i;
          float v = (k < 10) ? ws[k * 128 + col] : 0.f;
          unsigned short h = f2bf(v);
          r[i] = pl ? f2bf(v - bf2f(h)) : h;
        }
        ubf[pl] = r;
      }
    }
    float bL1 = bl[ft * 16 + rsel];

    f32x4 a1[3];
#pragma unroll
    for (int mt = 0; mt < 3; ++mt) a1[mt] = f32x4{0.f, 0.f, 0.f, 0.f};
#pragma unroll
    for (int mt = 0; mt < 3; ++mt) {
      int node = (ng * 3 + mt) * 16 + rsel;
      u16x8 af = *(const u16x8*)(lds + CNT + kh * 1536 + node * 16);
      a1[mt] = mfma16(af, ubf[0], a1[mt]);
      a1[mt] = mfma16(af, ubf[1], a1[mt]);
    }
#pragma unroll
    for (int mt = 0; mt < 3; ++mt) {
      int node0 = (ng * 3 + mt) * 16 + kh * 4;
      int feat = ft * 16 + rsel;
      f32x4 v;
#pragma unroll
      for (int r = 0; r < 4; ++r) {
        float u = fmaxf(a1[mt][r] + bL1, 0.f);
        v[r] = (node0 + r < 81) ? u : 0.f;
      }
      u16x4 hi, lo;
      split4(v, hi, lo);
      int base = (node0 >> 3) * 2048 + feat * 16 + (node0 & 7) * 2;
      *(u16x4*)(lds + HB + base) = hi;
      *(u16x4*)(lds + HB + 24576 + base) = lo;
    }
  }

  // agg: g^T = h^T (A+I)   (A exact, h hi/lo -> 2 products); epi -> gbuf
  auto do_agg = [&]() {
    f32x4 ag[3];
#pragma unroll
    for (int j = 0; j < 3; ++j) ag[j] = f32x4{0.f, 0.f, 0.f, 0.f};
#pragma unroll
    for (int ks = 0; ks < 3; ++ks) {
      int feat = ft * 16 + rsel;
      int ba = (ks * 4 + kh) * 2048 + feat * 16;
      u16x8 ah = *(const u16x8*)(lds + HB + ba);
      u16x8 al = *(const u16x8*)(lds + HB + 24576 + ba);
#pragma unroll
      for (int j = 0; j < 3; ++j) {
        ag[j] = mfma16(ah, abf[j][ks], ag[j]);
        ag[j] = mfma16(al, abf[j][ks], ag[j]);
      }
    }
#pragma unroll
    for (int j = 0; j < 3; ++j) {
      int node = (ng * 3 + j) * 16 + rsel;
      int f0 = ft * 16 + kh * 4;
      u16x4 hi, lo;
      split4(ag[j], hi, lo);
      int base = (f0 >> 3) * 1536 + node * 16 + (f0 & 7) * 2;
      *(u16x4*)(lds + GB + base) = hi;
      *(u16x4*)(lds + GB + 24576 + base) = lo;
    }
  };

  // ---- GCN layers 2..5 (uniform orientation; l==5 peeled below) ----
#pragma unroll 1
  for (int l = 1; l <= 4; ++l) {
    __syncthreads();                     // hbuf ready; gbuf free
    float bw = bl[l * 128 + ft * 16 + rsel];

    do_agg();
    __syncthreads();                     // gbuf ready; hbuf free

    // W-GEMM: h' = g (W/21): 3-product hi/lo
    f32x4 wc[3];
#pragma unroll
    for (int mt = 0; mt < 3; ++mt) wc[mt] = f32x4{0.f, 0.f, 0.f, 0.f};
#pragma unroll
    for (int ks = 0; ks < 4; ++ks) {
      u16x8 gh[3], gl[3];
#pragma unroll
      for (int mt = 0; mt < 3; ++mt) {
        int node = (ng * 3 + mt) * 16 + rsel;
        int ba = (ks * 4 + kh) * 1536 + node * 16;
        gh[mt] = *(const u16x8*)(lds + GB + ba);
        gl[mt] = *(const u16x8*)(lds + GB + 24576 + ba);
      }
#pragma unroll
      for (int mt = 0; mt < 3; ++mt) {
        wc[mt] = mfma16(gh[mt], wbf[ks][0], wc[mt]);
        wc[mt] = mfma16(gh[mt], wbf[ks][1], wc[mt]);
        wc[mt] = mfma16(gl[mt], wbf[ks][0], wc[mt]);
      }
    }
    // prefetch next blob (blob l: W_{l+1}; at l==4 that's the flip's W, same ft)
    loadWB(l);
    // epi: bias+relu+mask -> hbuf [feat][node]
#pragma unroll
    for (int mt = 0; mt < 3; ++mt) {
      int node0 = (ng * 3 + mt) * 16 + kh * 4;
      int feat = ft * 16 + rsel;
      f32x4 v;
#pragma unroll
      for (int r = 0; r < 4; ++r) {
        float u = fmaxf(wc[mt][r] + bw, 0.f);
        v[r] = (node0 + r < 81) ? u : 0.f;
      }
      u16x4 hi, lo;
      split4(v, hi, lo);
      int base = (node0 >> 3) * 2048 + feat * 16 + (node0 & 7) * 2;
      *(u16x4*)(lds + HB + base) = hi;
      *(u16x4*)(lds + HB + 24576 + base) = lo;
    }
  }

  // ---- layer 6 (l==5), peeled: agg, then flipped h6^T = (W/21)^T g^T ----
  __syncthreads();                       // hbuf ready
  do_agg();
  __syncthreads();                       // gbuf ready; hbuf free

  u16x8 wo[4][2];                        // Wout frags (tight live range)
  {
    float b5[4];
#pragma unroll
    for (int r = 0; r < 4; ++r) b5[r] = bl[5 * 128 + ft * 16 + kh * 4 + r];
    f32x4 wc[3];
#pragma unroll
    for (int j = 0; j < 3; ++j) wc[j] = f32x4{0.f, 0.f, 0.f, 0.f};
#pragma unroll
    for (int ks = 0; ks < 4; ++ks) {
      u16x8 gh[3], gl[3];
#pragma unroll
      for (int j = 0; j < 3; ++j) {
        int node = (ng * 3 + j) * 16 + rsel;
        int ba = (ks * 4 + kh) * 1536 + node * 16;
        gh[j] = *(const u16x8*)(lds + GB + ba);
        gl[j] = *(const u16x8*)(lds + GB + 24576 + ba);
      }
#pragma unroll
      for (int j = 0; j < 3; ++j) {
        wc[j] = mfma16(wbf[ks][0], gh[j], wc[j]);
        wc[j] = mfma16(wbf[ks][0], gl[j], wc[j]);
        wc[j] = mfma16(wbf[ks][1], gh[j], wc[j]);
      }
    }
    // load Wout frags now (latency hidden under epi + barrier)
#pragma unroll
    for (int ks = 0; ks < 4; ++ks)
#pragma unroll
      for (int pl = 0; pl < 2; ++pl) {
        if constexpr (PRE)
          wo[ks][pl] = *(const u16x8*)(G + OFF_WOUT + (ks * 2 + pl) * 1024 + lane * 16);
        else {
          int col = rsel, k0 = ks * 32 + kh * 8;
          u16x8 r;
#pragma unroll
          for (int i = 0; i < 8; ++i) {
            float v = (col < 9) ? Wout[(k0 + i) * 9 + col] : 0.f;
            unsigned short h = f2bf(v);
            r[i] = pl ? f2bf(v - bf2f(h)) : h;
          }
          wo[ks][pl] = r;
        }
      }
    // epi: C row=outfeat(4 consec), col=node -> h6buf[node][feat] b64-packed
#pragma unroll
    for (int j = 0; j < 3; ++j) {
      int node = (ng * 3 + j) * 16 + rsel;
      int f0 = ft * 16 + kh * 4;
      f32x4 v;
#pragma unroll
      for (int r = 0; r < 4; ++r) {
        float u = fmaxf(wc[j][r] + b5[r], 0.f);
        v[r] = (node < 81) ? u : 0.f;
      }
      u16x4 hi, lo;
      split4(v, hi, lo);
      int base = (f0 >> 3) * 1536 + node * 16 + (f0 & 7) * 2;
      *(u16x4*)(lds + HB + base) = hi;
      *(u16x4*)(lds + HB + 24576 + base) = lo;
    }
  }

  __syncthreads();
  // ---- output GEMM: logits = h6 @ Wout + bout (waves 0..5, 1 tile each) ----
  if (w < 6) {
    f32x4 oc = f32x4{0.f, 0.f, 0.f, 0.f};
#pragma unroll
    for (int ks = 0; ks < 4; ++ks) {
      int node = w * 16 + rsel;
      int ba = (ks * 4 + kh) * 1536 + node * 16;
      u16x8 hh = *(const u16x8*)(lds + HB + ba);
      u16x8 hl = *(const u16x8*)(lds + HB + 24576 + ba);
      oc = mfma16(hh, wo[ks][0], oc);
      oc = mfma16(hh, wo[ks][1], oc);
      oc = mfma16(hl, wo[ks][0], oc);
    }
    int colo = rsel;
    if (colo < 9) {
      float bo = bout[colo];
#pragma unroll
      for (int r = 0; r < 4; ++r) {
        int node = w * 16 + kh * 4 + r;
        if (node < 81) out[b * 729 + node * 9 + colo] = oc[r] + bo;
      }
    }
  }
}

// ------------------------------- launcher ------------------------------------
extern "C" void kernel_launch(void* const* d_in, const int* in_sizes, int n_in,
                              void* d_out, int out_size, void* d_ws, size_t ws_size,
                              hipStream_t stream) {
  const int*   x    = (const int*)d_in[0];
  const float* Win  = (const float*)d_in[1];
  const float* bin  = (const float*)d_in[2];
  const float* Wl   = (const float*)d_in[3];
  const float* blay = (const float*)d_in[4];
  const float* Wout = (const float*)d_in[5];
  const float* bout = (const float*)d_in[6];
  float* out = (float*)d_out;
  int nB = in_sizes[0] / 81;

  bool pre = ws_size >= WS_NEED;
  gnn_setup<<<1, 256, 0, stream>>>(Win, bin, Wl, (float*)d_ws);     // U -> ws+0
  if (pre)
    gnn_pack<<<362, 64, 0, stream>>>(Wl, Wout, (const float*)d_ws, (char*)d_ws);

  if (pre) {
    hipFuncSetAttribute((const void*)gnn_main<true>,
                        hipFuncAttributeMaxDynamicSharedMemorySize, LDS_SZ);
    gnn_main<true><<<nB, 1024, LDS_SZ, stream>>>(x, Wl, blay, Wout, bout,
                                                 (const float*)d_ws, out, nB);
  } else {
    hipFuncSetAttribute((const void*)gnn_main<false>,
                        hipFuncAttributeMaxDynamicSharedMemorySize, LDS_SZ);
    gnn_main<false><<<nB, 1024, LDS_SZ, stream>>>(x, Wl, blay, Wout, bout,
                                                  (const float*)d_ws, out, nB);
  }
}

// Round 6
// 655.408 us; speedup vs baseline: 1.5680x; 1.0244x over previous
//
#include <hip/hip_runtime.h>
#include <hip/hip_bf16.h>

// ---------------------------------------------------------------------------
// Sudoku GCN, fully fused, MFMA-everything.
//   h_{l+1} = relu( (A+I) h_l * (W_l/21) + b_l ),  A+I exact 0/1 in bf16.
// Orientation ping-pong (no transposed reads, all epi writes b64-packed):
//   hbuf = h^T [feat][node] (chunk-major), gbuf = g [node][feat] (chunk-major)
//   agg : g^T = h^T (A+I)     reads hbuf rows, writes gbuf packed
//   gemm: h'  = g (W/21)      reads gbuf rows, writes hbuf packed
//   l=6 : h6^T = W^T g^T      writes h6 as [node][feat] for the output GEMM
// Layer 1 collapsed: h1 = relu(Cnt @ U + b1), U = relu(Win+bin)@W1/21.
// R6: register-liveness fix (R5 spilled 590 MB: 1024-thr block caps the
// unified file at 128 regs/wave and flip-phase peak was ~136). wbf is now
// per-phase (issued before do_agg so latency hides under agg MFMAs, dies at
// the epi); GEMMs hold ONE gh/gl pair (8 regs, was 24); wo loads after the
// flip epi and only on waves w<6. Peak ~100 regs.
// ---------------------------------------------------------------------------

typedef short          s16x8 __attribute__((ext_vector_type(8)));
typedef unsigned short u16x8 __attribute__((ext_vector_type(8)));
typedef unsigned short u16x4 __attribute__((ext_vector_type(4)));
typedef float          f32x4 __attribute__((ext_vector_type(4)));

#define HB   0        // hbuf: [2 pl][12 chunk][128 feat][16B]  plane stride 24576
#define GB   49152    // gbuf: [2 pl][16 chunk][96 node][16B]   plane stride 24576
#define CNT  98304    // cnt : [4 chunk][96 node][16B] = 6144
#define XC   104448   // x cache: 81 ints
#define LDS_SZ 104832

#define OFF_WB   5120     // [l 0..4][nt 0..7][ks 0..3][pl 0..1] x 1024B
#define OFF_AB   332800   // [nt 0..5][ks 0..2] x 1024B  (A+I, hi only, exact)
#define OFF_UB   351232   // [nt 0..7][pl] x 1024B
#define OFF_WOUT 367616   // [ks 0..3][pl] x 1024B
#define WS_NEED  375808

__device__ __forceinline__ unsigned short f2bf(float f) {   // RTNE via v_cvt
  return __builtin_bit_cast(unsigned short, __float2bfloat16(f));
}
__device__ __forceinline__ float bf2f(unsigned short h) {
  unsigned u = ((unsigned)h) << 16;
  return __builtin_bit_cast(float, u);
}
__device__ __forceinline__ f32x4 mfma16(u16x8 a, u16x8 b, f32x4 c) {
  return __builtin_amdgcn_mfma_f32_16x16x32_bf16(
      __builtin_bit_cast(s16x8, a), __builtin_bit_cast(s16x8, b), c, 0, 0, 0);
}
__device__ __forceinline__ void split4(f32x4 v, u16x4& hi, u16x4& lo) {
#pragma unroll
  for (int r = 0; r < 4; ++r) {
    unsigned short h = f2bf(v[r]);
    hi[r] = h;
    lo[r] = f2bf(v[r] - bf2f(h));
  }
}
__device__ __forceinline__ bool adjf(int r, int c) {
  if (r >= 81 || c >= 81) return false;
  int ri = r / 9, rj = r % 9, ci = c / 9, cj = c % 9;
  return ri == ci || rj == cj || (ri / 3 == ci / 3 && rj / 3 == cj / 3);
}
__device__ __forceinline__ u16x8 makeAB(int nt, int ks, int lane) {
  int col = nt * 16 + (lane & 15), k0 = ks * 32 + (lane >> 4) * 8;
  u16x8 r;
#pragma unroll
  for (int i = 0; i < 8; ++i) r[i] = adjf(k0 + i, col) ? 0x3F80 : 0;
  return r;
}

// ---------------- setup1: U[10][128] = relu(Win+bin) @ W1 / 21 (f32, ws+0) ---
extern "C" __global__ void gnn_setup(const float* __restrict__ Win,
                                     const float* __restrict__ bin,
                                     const float* __restrict__ W1,
                                     float* __restrict__ U) {
  __shared__ float V[1280];
  int t = threadIdx.x;
#pragma unroll
  for (int q = 0; q < 5; ++q) {
    int idx = t + 256 * q;
    V[idx] = fmaxf(Win[idx] + bin[idx & 127], 0.f);
  }
  __syncthreads();
#pragma unroll
  for (int p = 0; p < 5; ++p) {
    int o = t + 256 * p;
    int d = o >> 7, c = o & 127;
    float s = 0.f;
    for (int f = 0; f < 128; ++f) s += V[d * 128 + f] * W1[f * 128 + c];
    U[o] = s * (1.f / 21.f);
  }
}

// ---------------- setup2: pack all B/A fragment blobs into ws ----------------
extern "C" __global__ void gnn_pack(const float* __restrict__ Wl,
                                    const float* __restrict__ Wout,
                                    const float* __restrict__ Uscr,
                                    char* __restrict__ G) {
  int unit = blockIdx.x, lane = threadIdx.x;
  int rsel = lane & 15, kh = lane >> 4;
  u16x8 r;
  char* dst;
  if (unit < 320) {                       // WB: ((l*8+nt)*4+ks)*2+pl
    int pl = unit & 1, ks = (unit >> 1) & 3, nt = (unit >> 3) & 7, l = unit >> 6;
    int col = nt * 16 + rsel, k0 = ks * 32 + kh * 8;
    const float* src = Wl + (l + 1) * 16384 + k0 * 128 + col;
#pragma unroll
    for (int i = 0; i < 8; ++i) {
      float v = src[i * 128] * (1.f / 21.f);
      unsigned short h = f2bf(v);
      r[i] = pl ? f2bf(v - bf2f(h)) : h;
    }
    dst = G + OFF_WB + unit * 1024 + lane * 16;
  } else if (unit < 338) {                // AB: nt*3+ks
    int u2 = unit - 320, nt = u2 / 3, ks = u2 % 3;
    r = makeAB(nt, ks, lane);
    dst = G + OFF_AB + u2 * 1024 + lane * 16;
  } else if (unit < 354) {                // UB: nt*2+pl
    int u2 = unit - 338, nt = u2 >> 1, pl = u2 & 1;
    int col = nt * 16 + rsel;
#pragma unroll
    for (int i = 0; i < 8; ++i) {
      int k = kh * 8 + i;
      float v = (k < 10) ? Uscr[k * 128 + col] : 0.f;
      unsigned short h = f2bf(v);
      r[i] = pl ? f2bf(v - bf2f(h)) : h;
    }
    dst = G + OFF_UB + u2 * 1024 + lane * 16;
  } else {                                // WOUT: ks*2+pl
    int u2 = unit - 354, ks = u2 >> 1, pl = u2 & 1;
    int col = rsel, k0 = ks * 32 + kh * 8;
#pragma unroll
    for (int i = 0; i < 8; ++i) {
      float v = (col < 9) ? Wout[(k0 + i) * 9 + col] : 0.f;
      unsigned short h = f2bf(v);
      r[i] = pl ? f2bf(v - bf2f(h)) : h;
    }
    dst = G + OFF_WOUT + u2 * 1024 + lane * 16;
  }
  *(u16x8*)dst = r;
}

// --------------------------------- main -------------------------------------
template <bool PRE>
__global__ void __launch_bounds__(1024, 4)
gnn_main(const int* __restrict__ x, const float* __restrict__ Wl,
         const float* __restrict__ bl, const float* __restrict__ Wout,
         const float* __restrict__ bout, const float* __restrict__ ws,
         float* __restrict__ out, int nB) {
  extern __shared__ char lds[];
  const int t = threadIdx.x, lane = t & 63, w = t >> 6;   // w 0..15
  const int rsel = lane & 15, kh = lane >> 4;
  const char* G = (const char*)ws;
  const int b = blockIdx.x;

  // uniform wave->tile mapping for ALL phases:
  const int ft = w >> 1;                 // feat tile 0..7 (L1 n, agg m, W n, flip m)
  const int ng = w & 1;                  // node group 0..1 (3 node-tiles each)

  // ---- persistent A+I fragments (exact, hi only): 36 VGPRs ----
  u16x8 abf[3][3];
#pragma unroll
  for (int j = 0; j < 3; ++j)
#pragma unroll
    for (int ks = 0; ks < 3; ++ks) {
      if constexpr (PRE)
        abf[j][ks] = *(const u16x8*)(G + OFF_AB + ((ng * 3 + j) * 3 + ks) * 1024 + lane * 16);
      else
        abf[j][ks] = makeAB(ng * 3 + j, ks, lane);
    }

  // per-phase W frags (NOT persistent; loaded at phase start, die at epi)
  u16x8 wbf[4][2];
  auto loadWB = [&](int blob) {
#pragma unroll
    for (int ks = 0; ks < 4; ++ks)
#pragma unroll
      for (int pl = 0; pl < 2; ++pl) {
        if constexpr (PRE) {
          wbf[ks][pl] = *(const u16x8*)(
              G + OFF_WB + ((((blob * 8 + ft) * 4 + ks) * 2 + pl) << 10) + lane * 16);
        } else {
          int colw = ft * 16 + rsel, k0 = ks * 32 + kh * 8;
          const float* src = Wl + (blob + 1) * 16384 + k0 * 128 + colw;
          u16x8 r;
#pragma unroll
          for (int i = 0; i < 8; ++i) {
            float v = src[i * 128] * (1.f / 21.f);
            unsigned short h = f2bf(v);
            r[i] = pl ? f2bf(v - bf2f(h)) : h;
          }
          wbf[ks][pl] = r;
        }
      }
  };

  // ---- x cache + digit counts -> cntbuf ----
  if (t < 81) ((int*)(lds + XC))[t] = x[b * 81 + t];
  __syncthreads();
  if (t < 96) {
    unsigned short cnt[16];
#pragma unroll
    for (int d = 0; d < 16; ++d) cnt[d] = 0;
    if (t < 81) {
      const int* xs = (const int*)(lds + XC);
      int n = t, i = n / 9, j = n - 9 * i;
      int bi = (i / 3) * 3, bj = (j / 3) * 3;
      int rv[9], cv[9], bv[9], rb3[3], cb3[3];
#pragma unroll
      for (int k = 0; k < 9; ++k) rv[k] = xs[i * 9 + k];
#pragma unroll
      for (int k = 0; k < 9; ++k) cv[k] = xs[k * 9 + j];
#pragma unroll
      for (int r2 = 0; r2 < 3; ++r2)
#pragma unroll
        for (int c2 = 0; c2 < 3; ++c2) bv[r2 * 3 + c2] = xs[(bi + r2) * 9 + (bj + c2)];
#pragma unroll
      for (int k = 0; k < 3; ++k) rb3[k] = xs[i * 9 + bj + k];
#pragma unroll
      for (int k = 0; k < 3; ++k) cb3[k] = xs[(bi + k) * 9 + j];
#pragma unroll
      for (int d = 0; d < 10; ++d) {
        int c = 0;
#pragma unroll
        for (int k = 0; k < 9; ++k) c += (rv[k] == d) + (cv[k] == d) + (bv[k] == d);
#pragma unroll
        for (int k = 0; k < 3; ++k) c -= (rb3[k] == d) + (cb3[k] == d);
        cnt[d] = f2bf((float)c);         // integers <=21: exact in bf16
      }
    }
    u16x8 c0, c1, z;
#pragma unroll
    for (int e = 0; e < 8; ++e) { c0[e] = cnt[e]; c1[e] = cnt[8 + e]; z[e] = 0; }
    *(u16x8*)(lds + CNT + 0 * 1536 + t * 16) = c0;
    *(u16x8*)(lds + CNT + 1 * 1536 + t * 16) = c1;
    *(u16x8*)(lds + CNT + 2 * 1536 + t * 16) = z;
    *(u16x8*)(lds + CNT + 3 * 1536 + t * 16) = z;
  }
  __syncthreads();

  // ---- L1 GEMM: h1 = relu(Cnt @ U + b1) -> hbuf [feat][node] -----
  {
    u16x8 ubf[2];                        // U B-frags [pl] (dead after L1)
#pragma unroll
    for (int pl = 0; pl < 2; ++pl) {
      if constexpr (PRE)
        ubf[pl] = *(const u16x8*)(G + OFF_UB + (ft * 2 + pl) * 1024 + lane * 16);
      else {
        int col = ft * 16 + rsel;
        u16x8 r;
#pragma unroll
        for (int i = 0; i < 8; ++i) {
          int k = kh * 8 + i;
          float v = (k < 10) ? ws[k * 128 + col] : 0.f;
          unsigned short h = f2bf(v);
          r[i] = pl ? f2bf(v - bf2f(h)) : h;
        }
        ubf[pl] = r;
      }
    }
    float bL1 = bl[ft * 16 + rsel];

    f32x4 a1[3];
#pragma unroll
    for (int mt = 0; mt < 3; ++mt) a1[mt] = f32x4{0.f, 0.f, 0.f, 0.f};
#pragma unroll
    for (int mt = 0; mt < 3; ++mt) {
      int node = (ng * 3 + mt) * 16 + rsel;
      u16x8 af = *(const u16x8*)(lds + CNT + kh * 1536 + node * 16);
      a1[mt] = mfma16(af, ubf[0], a1[mt]);
      a1[mt] = mfma16(af, ubf[1], a1[mt]);
    }
#pragma unroll
    for (int mt = 0; mt < 3; ++mt) {
      int node0 = (ng * 3 + mt) * 16 + kh * 4;
      int feat = ft * 16 + rsel;
      f32x4 v;
#pragma unroll
      for (int r = 0; r < 4; ++r) {
        float u = fmaxf(a1[mt][r] + bL1, 0.f);
        v[r] = (node0 + r < 81) ? u : 0.f;
      }
      u16x4 hi, lo;
      split4(v, hi, lo);
      int base = (node0 >> 3) * 2048 + feat * 16 + (node0 & 7) * 2;
      *(u16x4*)(lds + HB + base) = hi;
      *(u16x4*)(lds + HB + 24576 + base) = lo;
    }
  }

  // agg: g^T = h^T (A+I)   (A exact, h hi/lo -> 2 products); epi -> gbuf
  auto do_agg = [&]() {
    f32x4 ag[3];
#pragma unroll
    for (int j = 0; j < 3; ++j) ag[j] = f32x4{0.f, 0.f, 0.f, 0.f};
#pragma unroll
    for (int ks = 0; ks < 3; ++ks) {
      int feat = ft * 16 + rsel;
      int ba = (ks * 4 + kh) * 2048 + feat * 16;
      u16x8 ah = *(const u16x8*)(lds + HB + ba);
      u16x8 al = *(const u16x8*)(lds + HB + 24576 + ba);
#pragma unroll
      for (int j = 0; j < 3; ++j) {
        ag[j] = mfma16(ah, abf[j][ks], ag[j]);
        ag[j] = mfma16(al, abf[j][ks], ag[j]);
      }
    }
#pragma unroll
    for (int j = 0; j < 3; ++j) {
      int node = (ng * 3 + j) * 16 + rsel;
      int f0 = ft * 16 + kh * 4;
      u16x4 hi, lo;
      split4(ag[j], hi, lo);
      int base = (f0 >> 3) * 1536 + node * 16 + (f0 & 7) * 2;
      *(u16x4*)(lds + GB + base) = hi;
      *(u16x4*)(lds + GB + 24576 + base) = lo;
    }
  };

  // ---- GCN layers 2..5 (uniform orientation; l==5 peeled below) ----
#pragma unroll 1
  for (int l = 1; l <= 4; ++l) {
    __syncthreads();                     // hbuf ready; gbuf free
    float bw = bl[l * 128 + ft * 16 + rsel];

    loadWB(l - 1);                       // issue early: latency hides under agg
    do_agg();
    __syncthreads();                     // gbuf ready; hbuf free

    // W-GEMM: h' = g (W/21): 3-product hi/lo; ONE gh/gl pair live at a time
    f32x4 wc[3];
#pragma unroll
    for (int mt = 0; mt < 3; ++mt) wc[mt] = f32x4{0.f, 0.f, 0.f, 0.f};
#pragma unroll
    for (int ks = 0; ks < 4; ++ks) {
#pragma unroll
      for (int mt = 0; mt < 3; ++mt) {
        int node = (ng * 3 + mt) * 16 + rsel;
        int ba = (ks * 4 + kh) * 1536 + node * 16;
        u16x8 gh = *(const u16x8*)(lds + GB + ba);
        u16x8 gl = *(const u16x8*)(lds + GB + 24576 + ba);
        wc[mt] = mfma16(gh, wbf[ks][0], wc[mt]);
        wc[mt] = mfma16(gh, wbf[ks][1], wc[mt]);
        wc[mt] = mfma16(gl, wbf[ks][0], wc[mt]);
      }
    }
    // epi: bias+relu+mask -> hbuf [feat][node]
#pragma unroll
    for (int mt = 0; mt < 3; ++mt) {
      int node0 = (ng * 3 + mt) * 16 + kh * 4;
      int feat = ft * 16 + rsel;
      f32x4 v;
#pragma unroll
      for (int r = 0; r < 4; ++r) {
        float u = fmaxf(wc[mt][r] + bw, 0.f);
        v[r] = (node0 + r < 81) ? u : 0.f;
      }
      u16x4 hi, lo;
      split4(v, hi, lo);
      int base = (node0 >> 3) * 2048 + feat * 16 + (node0 & 7) * 2;
      *(u16x4*)(lds + HB + base) = hi;
      *(u16x4*)(lds + HB + 24576 + base) = lo;
    }
  }

  // ---- layer 6 (l==5), peeled: agg, then flipped h6^T = (W/21)^T g^T ----
  __syncthreads();                       // hbuf ready
  loadWB(4);                             // flip weights; hides under agg
  do_agg();
  __syncthreads();                       // gbuf ready; hbuf free

  {
    float b5[4];
#pragma unroll
    for (int r = 0; r < 4; ++r) b5[r] = bl[5 * 128 + ft * 16 + kh * 4 + r];
    f32x4 wc[3];
#pragma unroll
    for (int j = 0; j < 3; ++j) wc[j] = f32x4{0.f, 0.f, 0.f, 0.f};
#pragma unroll
    for (int ks = 0; ks < 4; ++ks) {
#pragma unroll
      for (int j = 0; j < 3; ++j) {
        int node = (ng * 3 + j) * 16 + rsel;
        int ba = (ks * 4 + kh) * 1536 + node * 16;
        u16x8 gh = *(const u16x8*)(lds + GB + ba);
        u16x8 gl = *(const u16x8*)(lds + GB + 24576 + ba);
        wc[j] = mfma16(wbf[ks][0], gh, wc[j]);
        wc[j] = mfma16(wbf[ks][0], gl, wc[j]);
        wc[j] = mfma16(wbf[ks][1], gh, wc[j]);
      }
    }
    // epi: C row=outfeat(4 consec), col=node -> h6buf[node][feat] b64-packed
#pragma unroll
    for (int j = 0; j < 3; ++j) {
      int node = (ng * 3 + j) * 16 + rsel;
      int f0 = ft * 16 + kh * 4;
      f32x4 v;
#pragma unroll
      for (int r = 0; r < 4; ++r) {
        float u = fmaxf(wc[j][r] + b5[r], 0.f);
        v[r] = (node < 81) ? u : 0.f;
      }
      u16x4 hi, lo;
      split4(v, hi, lo);
      int base = (f0 >> 3) * 1536 + node * 16 + (f0 & 7) * 2;
      *(u16x4*)(lds + HB + base) = hi;
      *(u16x4*)(lds + HB + 24576 + base) = lo;
    }
  }

  // ---- output GEMM: logits = h6 @ Wout + bout (waves 0..5, 1 tile each) ----
  u16x8 wo[4][2];                        // loaded AFTER flip (gh/gl/wc dead)
  if (w < 6) {
#pragma unroll
    for (int ks = 0; ks < 4; ++ks)
#pragma unroll
      for (int pl = 0; pl < 2; ++pl) {
        if constexpr (PRE)
          wo[ks][pl] = *(const u16x8*)(G + OFF_WOUT + (ks * 2 + pl) * 1024 + lane * 16);
        else {
          int col = rsel, k0 = ks * 32 + kh * 8;
          u16x8 r;
#pragma unroll
          for (int i = 0; i < 8; ++i) {
            float v = (col < 9) ? Wout[(k0 + i) * 9 + col] : 0.f;
            unsigned short h = f2bf(v);
            r[i] = pl ? f2bf(v - bf2f(h)) : h;
          }
          wo[ks][pl] = r;
        }
      }
  }
  __syncthreads();
  if (w < 6) {
    f32x4 oc = f32x4{0.f, 0.f, 0.f, 0.f};
#pragma unroll
    for (int ks = 0; ks < 4; ++ks) {
      int node = w * 16 + rsel;
      int ba = (ks * 4 + kh) * 1536 + node * 16;
      u16x8 hh = *(const u16x8*)(lds + HB + ba);
      u16x8 hl = *(const u16x8*)(lds + HB + 24576 + ba);
      oc = mfma16(hh, wo[ks][0], oc);
      oc = mfma16(hh, wo[ks][1], oc);
      oc = mfma16(hl, wo[ks][0], oc);
    }
    int colo = rsel;
    if (colo < 9) {
      float bo = bout[colo];
#pragma unroll
      for (int r = 0; r < 4; ++r) {
        int node = w * 16 + kh * 4 + r;
        if (node < 81) out[b * 729 + node * 9 + colo] = oc[r] + bo;
      }
    }
  }
}

// ------------------------------- launcher ------------------------------------
extern "C" void kernel_launch(void* const* d_in, const int* in_sizes, int n_in,
                              void* d_out, int out_size, void* d_ws, size_t ws_size,
                              hipStream_t stream) {
  const int*   x    = (const int*)d_in[0];
  const float* Win  = (const float*)d_in[1];
  const float* bin  = (const float*)d_in[2];
  const float* Wl   = (const float*)d_in[3];
  const float* blay = (const float*)d_in[4];
  const float* Wout = (const float*)d_in[5];
  const float* bout = (const float*)d_in[6];
  float* out = (float*)d_out;
  int nB = in_sizes[0] / 81;

  bool pre = ws_size >= WS_NEED;
  gnn_setup<<<1, 256, 0, stream>>>(Win, bin, Wl, (float*)d_ws);     // U -> ws+0
  if (pre)
    gnn_pack<<<362, 64, 0, stream>>>(Wl, Wout, (const float*)d_ws, (char*)d_ws);

  if (pre) {
    hipFuncSetAttribute((const void*)gnn_main<true>,
                        hipFuncAttributeMaxDynamicSharedMemorySize, LDS_SZ);
    gnn_main<true><<<nB, 1024, LDS_SZ, stream>>>(x, Wl, blay, Wout, bout,
                                                 (const float*)d_ws, out, nB);
  } else {
    hipFuncSetAttribute((const void*)gnn_main<false>,
                        hipFuncAttributeMaxDynamicSharedMemorySize, LDS_SZ);
    gnn_main<false><<<nB, 1024, LDS_SZ, stream>>>(x, Wl, blay, Wout, bout,
                                                  (const float*)d_ws, out, nB);
  }
}

// Round 7
// 631.359 us; speedup vs baseline: 1.6277x; 1.0381x over previous
//
#include <hip/hip_runtime.h>
#include <hip/hip_bf16.h>

// ---------------------------------------------------------------------------
// Sudoku GCN, fully fused, MFMA-everything.
//   h_{l+1} = relu( (A+I) h_l * (W_l/21) + b_l ),  A+I exact 0/1 in bf16.
// Orientation ping-pong (no transposed reads, all epi writes b64-packed):
//   hbuf = h^T [feat][node] (chunk-major), gbuf = g [node][feat] (chunk-major)
//   agg : g^T = h^T (A+I)     reads hbuf rows, writes gbuf packed
//   gemm: h'  = g (W/21)      reads gbuf rows, writes hbuf packed
//   l=6 : h6^T = W^T g^T      writes h6 as [node][feat] for the output GEMM
// Layer 1 collapsed: h1 = relu(Cnt @ U + b1), U = relu(Win+bin)@W1/21.
// R7: kill the last spill (R6: 161 MB scratch, demand ~134 > 128-reg cap of
// a 1024-thr block). The 36-reg persistent A+I frags move to LDS: only 18
// distinct 1KB blobs exist block-wide (6 node-tiles x 3 k-chunks); staged
// once into spare LDS, ds_read_b128 per use in do_agg (can't hoist across
// barriers). Peak reg demand ~95 < 128 -> no spill.
// ---------------------------------------------------------------------------

typedef short          s16x8 __attribute__((ext_vector_type(8)));
typedef unsigned short u16x8 __attribute__((ext_vector_type(8)));
typedef unsigned short u16x4 __attribute__((ext_vector_type(4)));
typedef float          f32x4 __attribute__((ext_vector_type(4)));

#define HB   0        // hbuf: [2 pl][12 chunk][128 feat][16B]  plane stride 24576
#define GB   49152    // gbuf: [2 pl][16 chunk][96 node][16B]   plane stride 24576
#define CNT  98304    // cnt : [4 chunk][96 node][16B] = 6144
#define XC   104448   // x cache: 81 ints
#define ABL  104832   // A+I frag blobs in LDS: 18 x 1024B
#define LDS_SZ (104832 + 18432)   // 123264

#define OFF_WB   5120     // [l 0..4][nt 0..7][ks 0..3][pl 0..1] x 1024B
#define OFF_AB   332800   // [nt 0..5][ks 0..2] x 1024B  (A+I, hi only, exact)
#define OFF_UB   351232   // [nt 0..7][pl] x 1024B
#define OFF_WOUT 367616   // [ks 0..3][pl] x 1024B
#define WS_NEED  375808

__device__ __forceinline__ unsigned short f2bf(float f) {   // RTNE via v_cvt
  return __builtin_bit_cast(unsigned short, __float2bfloat16(f));
}
__device__ __forceinline__ float bf2f(unsigned short h) {
  unsigned u = ((unsigned)h) << 16;
  return __builtin_bit_cast(float, u);
}
__device__ __forceinline__ f32x4 mfma16(u16x8 a, u16x8 b, f32x4 c) {
  return __builtin_amdgcn_mfma_f32_16x16x32_bf16(
      __builtin_bit_cast(s16x8, a), __builtin_bit_cast(s16x8, b), c, 0, 0, 0);
}
__device__ __forceinline__ void split4(f32x4 v, u16x4& hi, u16x4& lo) {
#pragma unroll
  for (int r = 0; r < 4; ++r) {
    unsigned short h = f2bf(v[r]);
    hi[r] = h;
    lo[r] = f2bf(v[r] - bf2f(h));
  }
}
__device__ __forceinline__ bool adjf(int r, int c) {
  if (r >= 81 || c >= 81) return false;
  int ri = r / 9, rj = r % 9, ci = c / 9, cj = c % 9;
  return ri == ci || rj == cj || (ri / 3 == ci / 3 && rj / 3 == cj / 3);
}
__device__ __forceinline__ u16x8 makeAB(int nt, int ks, int lane) {
  int col = nt * 16 + (lane & 15), k0 = ks * 32 + (lane >> 4) * 8;
  u16x8 r;
#pragma unroll
  for (int i = 0; i < 8; ++i) r[i] = adjf(k0 + i, col) ? 0x3F80 : 0;
  return r;
}

// ---------------- setup1: U[10][128] = relu(Win+bin) @ W1 / 21 (f32, ws+0) ---
extern "C" __global__ void gnn_setup(const float* __restrict__ Win,
                                     const float* __restrict__ bin,
                                     const float* __restrict__ W1,
                                     float* __restrict__ U) {
  __shared__ float V[1280];
  int t = threadIdx.x;
#pragma unroll
  for (int q = 0; q < 5; ++q) {
    int idx = t + 256 * q;
    V[idx] = fmaxf(Win[idx] + bin[idx & 127], 0.f);
  }
  __syncthreads();
#pragma unroll
  for (int p = 0; p < 5; ++p) {
    int o = t + 256 * p;
    int d = o >> 7, c = o & 127;
    float s = 0.f;
    for (int f = 0; f < 128; ++f) s += V[d * 128 + f] * W1[f * 128 + c];
    U[o] = s * (1.f / 21.f);
  }
}

// ---------------- setup2: pack all B/A fragment blobs into ws ----------------
extern "C" __global__ void gnn_pack(const float* __restrict__ Wl,
                                    const float* __restrict__ Wout,
                                    const float* __restrict__ Uscr,
                                    char* __restrict__ G) {
  int unit = blockIdx.x, lane = threadIdx.x;
  int rsel = lane & 15, kh = lane >> 4;
  u16x8 r;
  char* dst;
  if (unit < 320) {                       // WB: ((l*8+nt)*4+ks)*2+pl
    int pl = unit & 1, ks = (unit >> 1) & 3, nt = (unit >> 3) & 7, l = unit >> 6;
    int col = nt * 16 + rsel, k0 = ks * 32 + kh * 8;
    const float* src = Wl + (l + 1) * 16384 + k0 * 128 + col;
#pragma unroll
    for (int i = 0; i < 8; ++i) {
      float v = src[i * 128] * (1.f / 21.f);
      unsigned short h = f2bf(v);
      r[i] = pl ? f2bf(v - bf2f(h)) : h;
    }
    dst = G + OFF_WB + unit * 1024 + lane * 16;
  } else if (unit < 338) {                // AB: nt*3+ks
    int u2 = unit - 320, nt = u2 / 3, ks = u2 % 3;
    r = makeAB(nt, ks, lane);
    dst = G + OFF_AB + u2 * 1024 + lane * 16;
  } else if (unit < 354) {                // UB: nt*2+pl
    int u2 = unit - 338, nt = u2 >> 1, pl = u2 & 1;
    int col = nt * 16 + rsel;
#pragma unroll
    for (int i = 0; i < 8; ++i) {
      int k = kh * 8 + i;
      float v = (k < 10) ? Uscr[k * 128 + col] : 0.f;
      unsigned short h = f2bf(v);
      r[i] = pl ? f2bf(v - bf2f(h)) : h;
    }
    dst = G + OFF_UB + u2 * 1024 + lane * 16;
  } else {                                // WOUT: ks*2+pl
    int u2 = unit - 354, ks = u2 >> 1, pl = u2 & 1;
    int col = rsel, k0 = ks * 32 + kh * 8;
#pragma unroll
    for (int i = 0; i < 8; ++i) {
      float v = (col < 9) ? Wout[(k0 + i) * 9 + col] : 0.f;
      unsigned short h = f2bf(v);
      r[i] = pl ? f2bf(v - bf2f(h)) : h;
    }
    dst = G + OFF_WOUT + u2 * 1024 + lane * 16;
  }
  *(u16x8*)dst = r;
}

// --------------------------------- main -------------------------------------
template <bool PRE>
__global__ void __launch_bounds__(1024, 4)
gnn_main(const int* __restrict__ x, const float* __restrict__ Wl,
         const float* __restrict__ bl, const float* __restrict__ Wout,
         const float* __restrict__ bout, const float* __restrict__ ws,
         float* __restrict__ out, int nB) {
  extern __shared__ char lds[];
  const int t = threadIdx.x, lane = t & 63, w = t >> 6;   // w 0..15
  const int rsel = lane & 15, kh = lane >> 4;
  const char* G = (const char*)ws;
  const int b = blockIdx.x;

  // uniform wave->tile mapping for ALL phases:
  const int ft = w >> 1;                 // feat tile 0..7 (L1 n, agg m, W n, flip m)
  const int ng = w & 1;                  // node group 0..1 (3 node-tiles each)

  // ---- stage A+I frag blobs into LDS (18 x 1KB, block-uniform) ----
  if constexpr (PRE) {
#pragma unroll
    for (int q = 0; q < 2; ++q) {
      int u = t + q * 1024;
      if (u < 1152)                      // 18 KB / 16 B
        *(u16x8*)(lds + ABL + u * 16) = *(const u16x8*)(G + OFF_AB + u * 16);
    }
  } else {
#pragma unroll
    for (int u = w; u < 18; u += 16)
      *(u16x8*)(lds + ABL + u * 1024 + lane * 16) = makeAB(u / 3, u % 3, lane);
  }

  // per-phase W frags (loaded at phase start, die at epi)
  u16x8 wbf[4][2];
  auto loadWB = [&](int blob) {
#pragma unroll
    for (int ks = 0; ks < 4; ++ks)
#pragma unroll
      for (int pl = 0; pl < 2; ++pl) {
        if constexpr (PRE) {
          wbf[ks][pl] = *(const u16x8*)(
              G + OFF_WB + ((((blob * 8 + ft) * 4 + ks) * 2 + pl) << 10) + lane * 16);
        } else {
          int colw = ft * 16 + rsel, k0 = ks * 32 + kh * 8;
          const float* src = Wl + (blob + 1) * 16384 + k0 * 128 + colw;
          u16x8 r;
#pragma unroll
          for (int i = 0; i < 8; ++i) {
            float v = src[i * 128] * (1.f / 21.f);
            unsigned short h = f2bf(v);
            r[i] = pl ? f2bf(v - bf2f(h)) : h;
          }
          wbf[ks][pl] = r;
        }
      }
  };

  // ---- x cache + digit counts -> cntbuf ----
  if (t < 81) ((int*)(lds + XC))[t] = x[b * 81 + t];
  __syncthreads();
  if (t < 96) {
    unsigned short cnt[16];
#pragma unroll
    for (int d = 0; d < 16; ++d) cnt[d] = 0;
    if (t < 81) {
      const int* xs = (const int*)(lds + XC);
      int n = t, i = n / 9, j = n - 9 * i;
      int bi = (i / 3) * 3, bj = (j / 3) * 3;
      int rv[9], cv[9], bv[9], rb3[3], cb3[3];
#pragma unroll
      for (int k = 0; k < 9; ++k) rv[k] = xs[i * 9 + k];
#pragma unroll
      for (int k = 0; k < 9; ++k) cv[k] = xs[k * 9 + j];
#pragma unroll
      for (int r2 = 0; r2 < 3; ++r2)
#pragma unroll
        for (int c2 = 0; c2 < 3; ++c2) bv[r2 * 3 + c2] = xs[(bi + r2) * 9 + (bj + c2)];
#pragma unroll
      for (int k = 0; k < 3; ++k) rb3[k] = xs[i * 9 + bj + k];
#pragma unroll
      for (int k = 0; k < 3; ++k) cb3[k] = xs[(bi + k) * 9 + j];
#pragma unroll
      for (int d = 0; d < 10; ++d) {
        int c = 0;
#pragma unroll
        for (int k = 0; k < 9; ++k) c += (rv[k] == d) + (cv[k] == d) + (bv[k] == d);
#pragma unroll
        for (int k = 0; k < 3; ++k) c -= (rb3[k] == d) + (cb3[k] == d);
        cnt[d] = f2bf((float)c);         // integers <=21: exact in bf16
      }
    }
    u16x8 c0, c1, z;
#pragma unroll
    for (int e = 0; e < 8; ++e) { c0[e] = cnt[e]; c1[e] = cnt[8 + e]; z[e] = 0; }
    *(u16x8*)(lds + CNT + 0 * 1536 + t * 16) = c0;
    *(u16x8*)(lds + CNT + 1 * 1536 + t * 16) = c1;
    *(u16x8*)(lds + CNT + 2 * 1536 + t * 16) = z;
    *(u16x8*)(lds + CNT + 3 * 1536 + t * 16) = z;
  }
  __syncthreads();

  // ---- L1 GEMM: h1 = relu(Cnt @ U + b1) -> hbuf [feat][node] -----
  {
    u16x8 ubf[2];                        // U B-frags [pl] (dead after L1)
#pragma unroll
    for (int pl = 0; pl < 2; ++pl) {
      if constexpr (PRE)
        ubf[pl] = *(const u16x8*)(G + OFF_UB + (ft * 2 + pl) * 1024 + lane * 16);
      else {
        int col = ft * 16 + rsel;
        u16x8 r;
#pragma unroll
        for (int i = 0; i < 8; ++i) {
          int k = kh * 8 + i;
          float v = (k < 10) ? ws[k * 128 + col] : 0.f;
          unsigned short h = f2bf(v);
          r[i] = pl ? f2bf(v - bf2f(h)) : h;
        }
        ubf[pl] = r;
      }
    }
    float bL1 = bl[ft * 16 + rsel];

    f32x4 a1[3];
#pragma unroll
    for (int mt = 0; mt < 3; ++mt) a1[mt] = f32x4{0.f, 0.f, 0.f, 0.f};
#pragma unroll
    for (int mt = 0; mt < 3; ++mt) {
      int node = (ng * 3 + mt) * 16 + rsel;
      u16x8 af = *(const u16x8*)(lds + CNT + kh * 1536 + node * 16);
      a1[mt] = mfma16(af, ubf[0], a1[mt]);
      a1[mt] = mfma16(af, ubf[1], a1[mt]);
    }
#pragma unroll
    for (int mt = 0; mt < 3; ++mt) {
      int node0 = (ng * 3 + mt) * 16 + kh * 4;
      int feat = ft * 16 + rsel;
      f32x4 v;
#pragma unroll
      for (int r = 0; r < 4; ++r) {
        float u = fmaxf(a1[mt][r] + bL1, 0.f);
        v[r] = (node0 + r < 81) ? u : 0.f;
      }
      u16x4 hi, lo;
      split4(v, hi, lo);
      int base = (node0 >> 3) * 2048 + feat * 16 + (node0 & 7) * 2;
      *(u16x4*)(lds + HB + base) = hi;
      *(u16x4*)(lds + HB + 24576 + base) = lo;
    }
  }

  // agg: g^T = h^T (A+I)  (A exact from LDS blobs, h hi/lo -> 2 products)
  auto do_agg = [&]() {
    f32x4 ag[3];
#pragma unroll
    for (int j = 0; j < 3; ++j) ag[j] = f32x4{0.f, 0.f, 0.f, 0.f};
#pragma unroll
    for (int ks = 0; ks < 3; ++ks) {
      int feat = ft * 16 + rsel;
      int ba = (ks * 4 + kh) * 2048 + feat * 16;
      u16x8 ah = *(const u16x8*)(lds + HB + ba);
      u16x8 al = *(const u16x8*)(lds + HB + 24576 + ba);
#pragma unroll
      for (int j = 0; j < 3; ++j) {
        u16x8 ab = *(const u16x8*)(lds + ABL + (((ng * 3 + j) * 3 + ks) << 10) + lane * 16);
        ag[j] = mfma16(ah, ab, ag[j]);
        ag[j] = mfma16(al, ab, ag[j]);
      }
    }
#pragma unroll
    for (int j = 0; j < 3; ++j) {
      int node = (ng * 3 + j) * 16 + rsel;
      int f0 = ft * 16 + kh * 4;
      u16x4 hi, lo;
      split4(ag[j], hi, lo);
      int base = (f0 >> 3) * 1536 + node * 16 + (f0 & 7) * 2;
      *(u16x4*)(lds + GB + base) = hi;
      *(u16x4*)(lds + GB + 24576 + base) = lo;
    }
  };

  // ---- GCN layers 2..5 (uniform orientation; l==5 peeled below) ----
#pragma unroll 1
  for (int l = 1; l <= 4; ++l) {
    __syncthreads();                     // hbuf ready; gbuf free
    float bw = bl[l * 128 + ft * 16 + rsel];

    loadWB(l - 1);                       // issue early: latency hides under agg
    do_agg();
    __syncthreads();                     // gbuf ready; hbuf free

    // W-GEMM: h' = g (W/21): 3-product hi/lo; ONE gh/gl pair live at a time
    f32x4 wc[3];
#pragma unroll
    for (int mt = 0; mt < 3; ++mt) wc[mt] = f32x4{0.f, 0.f, 0.f, 0.f};
#pragma unroll
    for (int ks = 0; ks < 4; ++ks) {
#pragma unroll
      for (int mt = 0; mt < 3; ++mt) {
        int node = (ng * 3 + mt) * 16 + rsel;
        int ba = (ks * 4 + kh) * 1536 + node * 16;
        u16x8 gh = *(const u16x8*)(lds + GB + ba);
        u16x8 gl = *(const u16x8*)(lds + GB + 24576 + ba);
        wc[mt] = mfma16(gh, wbf[ks][0], wc[mt]);
        wc[mt] = mfma16(gh, wbf[ks][1], wc[mt]);
        wc[mt] = mfma16(gl, wbf[ks][0], wc[mt]);
      }
    }
    // epi: bias+relu+mask -> hbuf [feat][node]
#pragma unroll
    for (int mt = 0; mt < 3; ++mt) {
      int node0 = (ng * 3 + mt) * 16 + kh * 4;
      int feat = ft * 16 + rsel;
      f32x4 v;
#pragma unroll
      for (int r = 0; r < 4; ++r) {
        float u = fmaxf(wc[mt][r] + bw, 0.f);
        v[r] = (node0 + r < 81) ? u : 0.f;
      }
      u16x4 hi, lo;
      split4(v, hi, lo);
      int base = (node0 >> 3) * 2048 + feat * 16 + (node0 & 7) * 2;
      *(u16x4*)(lds + HB + base) = hi;
      *(u16x4*)(lds + HB + 24576 + base) = lo;
    }
  }

  // ---- layer 6 (l==5), peeled: agg, then flipped h6^T = (W/21)^T g^T ----
  __syncthreads();                       // hbuf ready
  loadWB(4);                             // flip weights; hides under agg
  do_agg();
  __syncthreads();                       // gbuf ready; hbuf free

  {
    float b5[4];
#pragma unroll
    for (int r = 0; r < 4; ++r) b5[r] = bl[5 * 128 + ft * 16 + kh * 4 + r];
    f32x4 wc[3];
#pragma unroll
    for (int j = 0; j < 3; ++j) wc[j] = f32x4{0.f, 0.f, 0.f, 0.f};
#pragma unroll
    for (int ks = 0; ks < 4; ++ks) {
#pragma unroll
      for (int j = 0; j < 3; ++j) {
        int node = (ng * 3 + j) * 16 + rsel;
        int ba = (ks * 4 + kh) * 1536 + node * 16;
        u16x8 gh = *(const u16x8*)(lds + GB + ba);
        u16x8 gl = *(const u16x8*)(lds + GB + 24576 + ba);
        wc[j] = mfma16(wbf[ks][0], gh, wc[j]);
        wc[j] = mfma16(wbf[ks][0], gl, wc[j]);
        wc[j] = mfma16(wbf[ks][1], gh, wc[j]);
      }
    }
    // epi: C row=outfeat(4 consec), col=node -> h6buf[node][feat] b64-packed
#pragma unroll
    for (int j = 0; j < 3; ++j) {
      int node = (ng * 3 + j) * 16 + rsel;
      int f0 = ft * 16 + kh * 4;
      f32x4 v;
#pragma unroll
      for (int r = 0; r < 4; ++r) {
        float u = fmaxf(wc[j][r] + b5[r], 0.f);
        v[r] = (node < 81) ? u : 0.f;
      }
      u16x4 hi, lo;
      split4(v, hi, lo);
      int base = (f0 >> 3) * 1536 + node * 16 + (f0 & 7) * 2;
      *(u16x4*)(lds + HB + base) = hi;
      *(u16x4*)(lds + HB + 24576 + base) = lo;
    }
  }

  // ---- output GEMM: logits = h6 @ Wout + bout (waves 0..5, 1 tile each) ----
  u16x8 wo[4][2];                        // loaded AFTER flip (gh/gl/wc dead)
  if (w < 6) {
#pragma unroll
    for (int ks = 0; ks < 4; ++ks)
#pragma unroll
      for (int pl = 0; pl < 2; ++pl) {
        if constexpr (PRE)
          wo[ks][pl] = *(const u16x8*)(G + OFF_WOUT + (ks * 2 + pl) * 1024 + lane * 16);
        else {
          int col = rsel, k0 = ks * 32 + kh * 8;
          u16x8 r;
#pragma unroll
          for (int i = 0; i < 8; ++i) {
            float v = (col < 9) ? Wout[(k0 + i) * 9 + col] : 0.f;
            unsigned short h = f2bf(v);
            r[i] = pl ? f2bf(v - bf2f(h)) : h;
          }
          wo[ks][pl] = r;
        }
      }
  }
  __syncthreads();
  if (w < 6) {
    f32x4 oc = f32x4{0.f, 0.f, 0.f, 0.f};
#pragma unroll
    for (int ks = 0; ks < 4; ++ks) {
      int node = w * 16 + rsel;
      int ba = (ks * 4 + kh) * 1536 + node * 16;
      u16x8 hh = *(const u16x8*)(lds + HB + ba);
      u16x8 hl = *(const u16x8*)(lds + HB + 24576 + ba);
      oc = mfma16(hh, wo[ks][0], oc);
      oc = mfma16(hh, wo[ks][1], oc);
      oc = mfma16(hl, wo[ks][0], oc);
    }
    int colo = rsel;
    if (colo < 9) {
      float bo = bout[colo];
#pragma unroll
      for (int r = 0; r < 4; ++r) {
        int node = w * 16 + kh * 4 + r;
        if (node < 81) out[b * 729 + node * 9 + colo] = oc[r] + bo;
      }
    }
  }
}

// ------------------------------- launcher ------------------------------------
extern "C" void kernel_launch(void* const* d_in, const int* in_sizes, int n_in,
                              void* d_out, int out_size, void* d_ws, size_t ws_size,
                              hipStream_t stream) {
  const int*   x    = (const int*)d_in[0];
  const float* Win  = (const float*)d_in[1];
  const float* bin  = (const float*)d_in[2];
  const float* Wl   = (const float*)d_in[3];
  const float* blay = (const float*)d_in[4];
  const float* Wout = (const float*)d_in[5];
  const float* bout = (const float*)d_in[6];
  float* out = (float*)d_out;
  int nB = in_sizes[0] / 81;

  bool pre = ws_size >= WS_NEED;
  gnn_setup<<<1, 256, 0, stream>>>(Win, bin, Wl, (float*)d_ws);     // U -> ws+0
  if (pre)
    gnn_pack<<<362, 64, 0, stream>>>(Wl, Wout, (const float*)d_ws, (char*)d_ws);

  if (pre) {
    hipFuncSetAttribute((const void*)gnn_main<true>,
                        hipFuncAttributeMaxDynamicSharedMemorySize, LDS_SZ);
    gnn_main<true><<<nB, 1024, LDS_SZ, stream>>>(x, Wl, blay, Wout, bout,
                                                 (const float*)d_ws, out, nB);
  } else {
    hipFuncSetAttribute((const void*)gnn_main<false>,
                        hipFuncAttributeMaxDynamicSharedMemorySize, LDS_SZ);
    gnn_main<false><<<nB, 1024, LDS_SZ, stream>>>(x, Wl, blay, Wout, bout,
                                                  (const float*)d_ws, out, nB);
  }
}